// Round 6
// baseline (643.721 us; speedup 1.0000x reference)
//
#include <hip/hip_runtime.h>

#define E_DIM 2048
#define H_NUM 16
#define D_HEAD 128
#define B_SZ 4
#define N_SEQ 2048
#define QKV_LD 2304   // E + 2*D
#define MROWS_T (B_SZ * N_SEQ)   // 8192
#define PLS 40        // P-tile LDS row stride in shorts (80 B, 16B-aligned)
#define SC2F 0.12751744802582937f  // log2(e)/sqrt(128)

typedef __attribute__((ext_vector_type(8))) __bf16 bfx8;
typedef __attribute__((ext_vector_type(8))) short sx8;
typedef __attribute__((ext_vector_type(4))) short sx4;
typedef __attribute__((ext_vector_type(2))) short sx2;
typedef __attribute__((ext_vector_type(4))) float fx4;

__device__ __forceinline__ fx4 mfma_bf16(bfx8 a, bfx8 b, fx4 c) {
    return __builtin_amdgcn_mfma_f32_16x16x32_bf16(a, b, c, 0, 0, 0);
}

// fp32 -> bf16 round-to-nearest-even (finite inputs only)
__device__ __forceinline__ short f2bf(float f) {
    unsigned u = __builtin_bit_cast(unsigned, f);
    u += 0x7FFFu + ((u >> 16) & 1u);
    return (short)(u >> 16);
}

// pack two fp32 -> one dword of two bf16 (lo=a, hi=b)
__device__ __forceinline__ int cvt_pk_bf16(float a, float b) {
    int r;
    asm("v_cvt_pk_bf16_f32 %0, %1, %2" : "=v"(r) : "v"(a), "v"(b));
    return r;
}

__device__ __forceinline__ void gld_lds16(const void* g, void* l) {
    __builtin_amdgcn_global_load_lds((__attribute__((address_space(1))) void*)(void*)g,
                                     (__attribute__((address_space(3))) void*)l, 16, 0, 0);
}

// ---------------- cast fp32 -> bf16 (elementwise) ----------------
__global__ __launch_bounds__(256) void cast_f32_bf16(const float* __restrict__ in,
                                                     short* __restrict__ out, int n) {
    int i = (blockIdx.x * 256 + threadIdx.x) * 4;
    if (i >= n) return;
    float4 v = *(const float4*)(in + i);
    sx4 r = {f2bf(v.x), f2bf(v.y), f2bf(v.z), f2bf(v.w)};
    *(sx4*)(out + i) = r;
}

// ---------------- transpose + cast: in[R][C] fp32 -> out[C][R] bf16 ----------------
__global__ __launch_bounds__(256) void transpose_cast(const float* __restrict__ in,
                                                      short* __restrict__ out, int R, int C) {
    __shared__ float tile[32][33];
    int c0 = blockIdx.x * 32, r0 = blockIdx.y * 32;
    int tx = threadIdx.x;
    for (int i = threadIdx.y; i < 32; i += 8)
        tile[i][tx] = in[(size_t)(r0 + i) * C + c0 + tx];
    __syncthreads();
    for (int i = threadIdx.y; i < 32; i += 8)
        out[(size_t)(c0 + i) * R + r0 + tx] = f2bf(tile[tx][i]);
}

// ---------------- transpose V slice of qkv -> vtg[128][8192] bf16 ----------------
// Key axis stored PERMUTED within each 32-key group: position 2i <- key i,
// position 2i+1 <- key 16+i (matches the P-store in attn; k-axis permutation of the
// PV MFMA cancels).
__global__ __launch_bounds__(256) void v_transpose(const short* __restrict__ qkv,
                                                   short* __restrict__ vtg) {
    __shared__ short tile[32][33];
    int r0 = blockIdx.x * 32;
    int d0 = blockIdx.y * 32;
    int tx = threadIdx.x;
    for (int i = threadIdx.y; i < 32; i += 8)
        tile[i][tx] = qkv[(size_t)(r0 + i) * QKV_LD + (E_DIM + D_HEAD) + d0 + tx];
    __syncthreads();
    int kp = ((tx & 15) << 1) | (tx >> 4);   // key-interleave permutation
    for (int i = threadIdx.y; i < 32; i += 8)
        vtg[(size_t)(d0 + i) * MROWS_T + r0 + kp] = tile[tx][i];
}

// ---------------- 128x128 GEMM (m97-structure) — used only for the small K/V slice ----------------
template <bool OUT_BF16, bool SCALE_Q>
__global__ __launch_bounds__(256) void gemm_bt(const short* __restrict__ A,
                                               const short* __restrict__ Bt,
                                               const float* __restrict__ bias,
                                               void* __restrict__ Cp,
                                               int M, int N, int ldc, int K) {
    __shared__ __align__(16) short As[128 * 32];
    __shared__ __align__(16) short Bs[128 * 32];
    const int tid = threadIdx.x, wave = tid >> 6, lane = tid & 63;
    const int quad = lane >> 4, l16 = lane & 15;

    const int gx = gridDim.x;
    int wg = blockIdx.y * gx + blockIdx.x;
    {
        const int nwg = gx * gridDim.y;
        const int qd = nwg >> 3, rm = nwg & 7;
        const int xcd = wg & 7, loc = wg >> 3;
        wg = (xcd < rm ? xcd * (qd + 1) : rm * (qd + 1) + (xcd - rm) * qd) + loc;
    }
    const int m0 = (wg / gx) * 128, n0 = (wg % gx) * 128;

    const int wm = (wave >> 1) * 64, wn = (wave & 1) * 64;
    const int srow = lane >> 2, scol = (lane & 3) * 8;

    fx4 acc[4][4];
#pragma unroll
    for (int mt = 0; mt < 4; ++mt)
#pragma unroll
        for (int nt = 0; nt < 4; ++nt) acc[mt][nt] = (fx4){0.f, 0.f, 0.f, 0.f};

    const short* Ag = A + (size_t)m0 * K;
    const short* Bg = Bt + (size_t)n0 * K;

    for (int k0 = 0; k0 < K; k0 += 32) {
#pragma unroll
        for (int i = 0; i < 2; ++i) {
            int chunk = wave * 2 + i;
            int row = chunk * 16 + srow;
            gld_lds16(Ag + (size_t)row * K + k0 + scol, &As[chunk * 512]);
            gld_lds16(Bg + (size_t)row * K + k0 + scol, &Bs[chunk * 512]);
        }
        __syncthreads();
        bfx8 af[4], bfr[4];
#pragma unroll
        for (int t = 0; t < 4; ++t) {
            af[t]  = *(const bfx8*)&As[(wm + t * 16 + l16) * 32 + quad * 8];
            bfr[t] = *(const bfx8*)&Bs[(wn + t * 16 + l16) * 32 + quad * 8];
        }
#pragma unroll
        for (int mt = 0; mt < 4; ++mt)
#pragma unroll
            for (int nt = 0; nt < 4; ++nt)
                acc[mt][nt] = mfma_bf16(af[mt], bfr[nt], acc[mt][nt]);
        __syncthreads();
    }

    const float scl = (SCALE_Q && n0 < E_DIM) ? SC2F : 1.0f;
    float bv[4];
#pragma unroll
    for (int nt = 0; nt < 4; ++nt) bv[nt] = bias[n0 + wn + nt * 16 + l16];

#pragma unroll
    for (int mt = 0; mt < 4; ++mt)
#pragma unroll
        for (int nt = 0; nt < 4; ++nt)
#pragma unroll
            for (int j = 0; j < 4; ++j) {
                int row = m0 + wm + mt * 16 + quad * 4 + j;
                int col = n0 + wn + nt * 16 + l16;
                float v = (acc[mt][nt][j] + bv[nt]) * scl;
                if (OUT_BF16)
                    ((short*)Cp)[(size_t)row * ldc + col] = f2bf(v);
                else
                    ((float*)Cp)[(size_t)row * ldc + col] = v;
            }
}

// ---------------- 256x256 8-phase GEMM (T2+T3+T4+T5), BK=64, 512 threads ----------------
// ROUND-2 SCHEDULE (harness-verified): phase's MFMA operands loaded in the same phase's
// mem region. Stage targets per tile t:
//   p0 -> (t+1).A.k1   p1 -> (t+1).B.k1   p2 -> (t+2).A.k0   p3 -> (t+2).B.k0
// One vmcnt(4) per tile (end of p3) guarantees the next tile's halves; vmcnt(0) at tails.
// Raw s_barrier (NOT __syncthreads -> would drain vmcnt); sched_barrier(0) fences phases.
// LDS swizzle: 16B-slot ^= (row>>1)&3 (write side via pre-swizzled global source).
template <bool OUT_BF16, bool SCALE_ALL>
__global__ __launch_bounds__(512) void gemm256(const short* __restrict__ A,
                                               const short* __restrict__ Bt,
                                               const float* __restrict__ bias,
                                               void* __restrict__ Cp,
                                               int M, int N, int ldc, int K) {
    __shared__ __align__(16) short lds[2][2][2][8192];   // [buf][kk][A=0/B=1][256*32]
    const int tid = threadIdx.x, wave = tid >> 6, lane = tid & 63;
    const int quad = lane >> 4, l16 = lane & 15;
    const int wmi = wave >> 2, wni = wave & 3;   // 2M x 4N wave grid
    const int m0 = blockIdx.y * 256, n0 = blockIdx.x * 256;

    const size_t rstep = (size_t)128 * K;
    const int srow = wave * 16 + (lane >> 2);
    const int sslot = (lane & 3) ^ ((lane >> 3) & 3);
    const short* Asrc = A + ((size_t)(m0 + srow)) * K + sslot * 8;
    const short* Bsrc = Bt + ((size_t)(n0 + srow)) * K + sslot * 8;

    auto stage = [&](const short* srcb, short* dstb, int kcol0) {
        gld_lds16(srcb + kcol0, dstb + wave * 512);
        gld_lds16(srcb + kcol0 + rstep, dstb + 4096 + wave * 512);
    };

    // fragment read offsets (swizzled): 16B-slot ^= (row>>1)&3
    const int swl = (l16 >> 1) & 3;
    const int aoff = (wmi * 128 + l16) * 32 + (quad ^ swl) * 8;
    const int boff = (wni * 64 + l16) * 32 + (quad ^ swl) * 8;

    fx4 acc[8][4];
#pragma unroll
    for (int m = 0; m < 8; ++m)
#pragma unroll
        for (int n = 0; n < 4; ++n) acc[m][n] = (fx4){0.f, 0.f, 0.f, 0.f};

    const int nt = K >> 6;

    // prologue: tile0 all 4 halves + tile1 k0; allow newest 2 halves outstanding
    stage(Asrc, &lds[0][0][0][0], 0);
    stage(Bsrc, &lds[0][0][1][0], 0);
    stage(Asrc, &lds[0][1][0][0], 32);
    stage(Bsrc, &lds[0][1][1][0], 32);
    stage(Asrc, &lds[1][0][0][0], 64);
    stage(Bsrc, &lds[1][0][1][0], 64);
    asm volatile("s_waitcnt vmcnt(4)");
    __builtin_amdgcn_s_barrier();
    __builtin_amdgcn_sched_barrier(0);

#pragma unroll 1
    for (int t = 0; t < nt; ++t) {
        const int cur = t & 1, nxt = cur ^ 1;
        const short* Ah0 = &lds[cur][0][0][0];
        const short* Bh0 = &lds[cur][0][1][0];
        const short* Ah1 = &lds[cur][1][0][0];
        const short* Bh1 = &lds[cur][1][1][0];
        const int kc = t * 64;
        bfx8 af[4], bf0[4], bf1[4];

        // ---- phase 0: kk=0, m 0-3 ----
#pragma unroll
        for (int n = 0; n < 4; ++n) bf0[n] = *(const bfx8*)&Bh0[boff + n * 512];
#pragma unroll
        for (int m = 0; m < 4; ++m) af[m] = *(const bfx8*)&Ah0[aoff + m * 512];
        if (t + 1 < nt) stage(Asrc, &lds[nxt][1][0][0], kc + 96);
        __builtin_amdgcn_s_barrier();
        __builtin_amdgcn_sched_barrier(0);
        __builtin_amdgcn_s_setprio(1);
#pragma unroll
        for (int m = 0; m < 4; ++m)
#pragma unroll
            for (int n = 0; n < 4; ++n) acc[m][n] = mfma_bf16(af[m], bf0[n], acc[m][n]);
        __builtin_amdgcn_s_setprio(0);
        __builtin_amdgcn_s_barrier();
        __builtin_amdgcn_sched_barrier(0);

        // ---- phase 1: kk=0, m 4-7 ----
#pragma unroll
        for (int m = 0; m < 4; ++m) af[m] = *(const bfx8*)&Ah0[aoff + (m + 4) * 512];
        if (t + 1 < nt) stage(Bsrc, &lds[nxt][1][1][0], kc + 96);
        __builtin_amdgcn_s_barrier();
        __builtin_amdgcn_sched_barrier(0);
        __builtin_amdgcn_s_setprio(1);
#pragma unroll
        for (int m = 0; m < 4; ++m)
#pragma unroll
            for (int n = 0; n < 4; ++n) acc[m + 4][n] = mfma_bf16(af[m], bf0[n], acc[m + 4][n]);
        __builtin_amdgcn_s_setprio(0);
        __builtin_amdgcn_s_barrier();
        __builtin_amdgcn_sched_barrier(0);

        // ---- phase 2: kk=1, m 0-3 ----
#pragma unroll
        for (int n = 0; n < 4; ++n) bf1[n] = *(const bfx8*)&Bh1[boff + n * 512];
#pragma unroll
        for (int m = 0; m < 4; ++m) af[m] = *(const bfx8*)&Ah1[aoff + m * 512];
        if (t + 2 < nt) stage(Asrc, &lds[cur][0][0][0], kc + 128);
        __builtin_amdgcn_s_barrier();
        __builtin_amdgcn_sched_barrier(0);
        __builtin_amdgcn_s_setprio(1);
#pragma unroll
        for (int m = 0; m < 4; ++m)
#pragma unroll
            for (int n = 0; n < 4; ++n) acc[m][n] = mfma_bf16(af[m], bf1[n], acc[m][n]);
        __builtin_amdgcn_s_setprio(0);
        __builtin_amdgcn_s_barrier();
        __builtin_amdgcn_sched_barrier(0);

        // ---- phase 3: kk=1, m 4-7 ----
#pragma unroll
        for (int m = 0; m < 4; ++m) af[m] = *(const bfx8*)&Ah1[aoff + (m + 4) * 512];
        if (t + 2 < nt) stage(Bsrc, &lds[cur][0][1][0], kc + 128);
        __builtin_amdgcn_s_barrier();
        __builtin_amdgcn_sched_barrier(0);
        __builtin_amdgcn_s_setprio(1);
#pragma unroll
        for (int m = 0; m < 4; ++m)
#pragma unroll
            for (int n = 0; n < 4; ++n) acc[m + 4][n] = mfma_bf16(af[m], bf1[n], acc[m + 4][n]);
        __builtin_amdgcn_s_setprio(0);
        if (t < nt - 2) asm volatile("s_waitcnt vmcnt(4)");
        else            asm volatile("s_waitcnt vmcnt(0)");
        __builtin_amdgcn_s_barrier();
        __builtin_amdgcn_sched_barrier(0);
    }

    const float scl = SCALE_ALL ? SC2F : 1.0f;
    float bvn[4];
#pragma unroll
    for (int n = 0; n < 4; ++n) bvn[n] = bias[n0 + wni * 64 + n * 16 + l16];

#pragma unroll
    for (int m = 0; m < 8; ++m)
#pragma unroll
        for (int n = 0; n < 4; ++n)
#pragma unroll
            for (int j = 0; j < 4; ++j) {
                int row = m0 + wmi * 128 + m * 16 + quad * 4 + j;
                int col = n0 + wni * 64 + n * 16 + l16;
                float v = (acc[m][n][j] + bvn[n]) * scl;
                if (OUT_BF16)
                    ((short*)Cp)[(size_t)row * ldc + col] = f2bf(v);
                else
                    ((float*)Cp)[(size_t)row * ldc + col] = v;
            }
}

// ---------------- Flash attention (multi-query, causal) ----------------
// ONE 128-row q-chunk per block (4 waves x 32 rows); grid 64 x 16 with chunk =
// 15 - blockIdx.y so heavy chunks (most k-tiles) dispatch first. 1024 blocks,
// LDS 42KB -> 3 blocks/CU resident (was grid-capped at 2): more TLP to hide the
// serial QK->softmax->PV chain. K/V LDS tiles use the involution slot-swizzle
// sigma(s) = s ^ ((s>>3)&7) on 16B slots (staging fetches global data of slot
// sigma(lane), reads apply sigma -> conflict-free ds_read_b128). V fragments are
// hoisted before the softmax so their DS latency overlaps the exp2 VALU work.
__global__ __launch_bounds__(256, 3) void attn_kernel(const short* __restrict__ qkv,
                                                      const short* __restrict__ vtg,
                                                      short* __restrict__ outp) {
    __shared__ __align__(16) short Ks[2][4096];
    __shared__ __align__(16) short Vt[2][4096];
    __shared__ __align__(16) short pl[4 * 32 * PLS];
    const int b = blockIdx.x >> 4, h = blockIdx.x & 15;
    const int chunk = 15 - blockIdx.y;   // heavy-first dispatch order
    const int tid = threadIdx.x, wave = tid >> 6, lane = tid & 63;
    const int quad = lane >> 4, l16 = lane & 15;
    const size_t baseRow = (size_t)b * N_SEQ;
    short* plw = pl + wave * 32 * PLS;

    // staging: lane l fetches logical slot sigma(l) = l ^ ((l>>3)&7)
    const int sl = lane ^ ((lane >> 3) & 7);
    const int srow = sl >> 2, sq = sl & 3;
    // read: logical slot (l16*4+quad) lives at physical slot ^ ((l16>>1)&7)
    const int rslot = ((l16 * 4 + quad) ^ ((l16 >> 1) & 7)) * 8;

    auto stage = [&](int k0, int bufi) {
#pragma unroll
        for (int i = 0; i < 2; ++i) {
            const int c = wave * 2 + i;
            gld_lds16(qkv + (baseRow + k0 + (c & 1) * 16 + srow) * QKV_LD + E_DIM +
                          (c >> 1) * 32 + sq * 8,
                      &Ks[bufi][c * 512]);
            gld_lds16(vtg + (size_t)(c * 16 + srow) * MROWS_T + baseRow + k0 + sq * 8,
                      &Vt[bufi][c * 512]);
        }
    };

    const int q0 = chunk * 128;
    const int wrow = q0 + wave * 32;

    bfx8 aq0[4], aq1[4];
    {
        const short* qb0 = qkv + (baseRow + wrow + l16) * QKV_LD + h * D_HEAD + quad * 8;
        const short* qb1 = qb0 + 16 * QKV_LD;
#pragma unroll
        for (int c = 0; c < 4; ++c) {
            aq0[c] = *(const bfx8*)(qb0 + c * 32);
            aq1[c] = *(const bfx8*)(qb1 + c * 32);
        }
    }

    fx4 accO0[8], accO1[8];
    float l0[4], l1[4];
#pragma unroll
    for (int dt = 0; dt < 8; ++dt) {
        accO0[dt] = (fx4){0.f, 0.f, 0.f, 0.f};
        accO1[dt] = (fx4){0.f, 0.f, 0.f, 0.f};
    }
#pragma unroll
    for (int j = 0; j < 4; ++j) { l0[j] = 0.f; l1[j] = 0.f; }

    const int nbulk = 4 * chunk;
    const int nkt = nbulk + 4;

    stage(0, 0);

#pragma unroll 1
    for (int kt = 0; kt < nkt; ++kt) {
        __syncthreads();   // buf[kt&1] ready (vmcnt drain; first iter drains stage(0,0))
        if (kt + 1 < nkt) stage((kt + 1) << 5, (kt + 1) & 1);
        const short* ks = Ks[kt & 1];
        const short* vs = Vt[kt & 1];
        const int k0 = kt << 5;

        fx4 s00 = {0.f, 0.f, 0.f, 0.f}, s01 = {0.f, 0.f, 0.f, 0.f};
        fx4 s10 = {0.f, 0.f, 0.f, 0.f}, s11 = {0.f, 0.f, 0.f, 0.f};
        __builtin_amdgcn_s_setprio(1);
#pragma unroll
        for (int dc = 0; dc < 4; ++dc) {
            bfx8 kf0 = *(const bfx8*)&ks[(dc * 2 + 0) * 512 + rslot];
            bfx8 kf1 = *(const bfx8*)&ks[(dc * 2 + 1) * 512 + rslot];
            s00 = mfma_bf16(aq0[dc], kf0, s00);
            s01 = mfma_bf16(aq0[dc], kf1, s01);
            s10 = mfma_bf16(aq1[dc], kf0, s10);
            s11 = mfma_bf16(aq1[dc], kf1, s11);
        }
        __builtin_amdgcn_s_setprio(0);

        // hoist V fragments: DS latency overlaps the softmax VALU below
        bfx8 bvr[8];
#pragma unroll
        for (int dt = 0; dt < 8; ++dt)
            bvr[dt] = *(const bfx8*)&vs[dt * 512 + rslot];

        const bool diag = kt >= nbulk;
#pragma unroll
        for (int j = 0; j < 4; ++j) {
            float e0 = __builtin_amdgcn_exp2f(s00[j]);
            float e1 = __builtin_amdgcn_exp2f(s01[j]);
            if (diag) {
                const int rb = wrow + quad * 4 + j;
                e0 = (k0 + l16 <= rb) ? e0 : 0.f;
                e1 = (k0 + 16 + l16 <= rb) ? e1 : 0.f;
            }
            l0[j] += e0 + e1;
            int pk = cvt_pk_bf16(e0, e1);
            *(sx2*)&plw[(quad * 4 + j) * PLS + 2 * l16] = __builtin_bit_cast(sx2, pk);
        }
#pragma unroll
        for (int j = 0; j < 4; ++j) {
            float e0 = __builtin_amdgcn_exp2f(s10[j]);
            float e1 = __builtin_amdgcn_exp2f(s11[j]);
            if (diag) {
                const int rb = wrow + 16 + quad * 4 + j;
                e0 = (k0 + l16 <= rb) ? e0 : 0.f;
                e1 = (k0 + 16 + l16 <= rb) ? e1 : 0.f;
            }
            l1[j] += e0 + e1;
            int pk = cvt_pk_bf16(e0, e1);
            *(sx2*)&plw[(16 + quad * 4 + j) * PLS + 2 * l16] = __builtin_bit_cast(sx2, pk);
        }

        sx8 aps0 = *(const sx8*)&plw[l16 * PLS + quad * 8];
        sx8 aps1 = *(const sx8*)&plw[(16 + l16) * PLS + quad * 8];
        bfx8 ap0 = __builtin_bit_cast(bfx8, aps0);
        bfx8 ap1 = __builtin_bit_cast(bfx8, aps1);
        __builtin_amdgcn_s_setprio(1);
#pragma unroll
        for (int dt = 0; dt < 8; ++dt) {
            accO0[dt] = mfma_bf16(ap0, bvr[dt], accO0[dt]);
            accO1[dt] = mfma_bf16(ap1, bvr[dt], accO1[dt]);
        }
        __builtin_amdgcn_s_setprio(0);
    }

#pragma unroll
    for (int off = 1; off < 16; off <<= 1)
#pragma unroll
        for (int j = 0; j < 4; ++j) {
            l0[j] += __shfl_xor(l0[j], off);
            l1[j] += __shfl_xor(l1[j], off);
        }
#pragma unroll
    for (int j = 0; j < 4; ++j) {
        float rl0 = 1.0f / l0[j];
        float rl1 = 1.0f / l1[j];
        size_t ob0 = (baseRow + wrow + quad * 4 + j) * (size_t)E_DIM + h * D_HEAD + l16;
        size_t ob1 = ob0 + (size_t)16 * E_DIM;
#pragma unroll
        for (int dt = 0; dt < 8; ++dt) {
            outp[ob0 + dt * 16] = f2bf(accO0[dt][j] * rl0);
            outp[ob1 + dt * 16] = f2bf(accO1[dt][j] * rl1);
        }
    }
}

extern "C" void kernel_launch(void* const* d_in, const int* in_sizes, int n_in,
                              void* d_out, int out_size, void* d_ws, size_t ws_size,
                              hipStream_t stream) {
    const float* x     = (const float*)d_in[0];
    const float* w_qkv = (const float*)d_in[1];
    const float* b_qkv = (const float*)d_in[2];
    const float* w_fc  = (const float*)d_in[3];
    const float* b_fc  = (const float*)d_in[4];
    float* out = (float*)d_out;

    const size_t MROWS = (size_t)B_SZ * N_SEQ;  // 8192
    short* xb    = (short*)d_ws;                         // 8192*2048
    short* wqkvt = xb + MROWS * E_DIM;                   // 2304*2048
    short* wfct  = wqkvt + (size_t)QKV_LD * E_DIM;       // 2048*2048
    short* qkvb  = wfct + (size_t)E_DIM * E_DIM;         // 8192*2304
    short* attnb = qkvb + MROWS * QKV_LD;                // 8192*2048
    short* vtg   = xb;   // reuse: xb dead after QKV GEMM

    cast_f32_bf16<<<dim3((int)(MROWS * E_DIM / 1024)), dim3(256), 0, stream>>>(
        x, xb, (int)(MROWS * E_DIM));
    transpose_cast<<<dim3(QKV_LD / 32, E_DIM / 32), dim3(32, 8), 0, stream>>>(
        w_qkv, wqkvt, E_DIM, QKV_LD);
    transpose_cast<<<dim3(E_DIM / 32, E_DIM / 32), dim3(32, 8), 0, stream>>>(
        w_fc, wfct, E_DIM, E_DIM);

    // QKV projection, Q columns (0..2047), scaled by SC2F: 256-grid, one clean round
    gemm256<true, true><<<dim3(E_DIM / 256, (int)(MROWS / 256)), dim3(512), 0, stream>>>(
        xb, wqkvt, b_qkv, qkvb, (int)MROWS, E_DIM, QKV_LD, E_DIM);
    // K/V columns (2048..2303), unscaled: small 128-block 128^2 dispatch
    gemm_bt<true, false><<<dim3(2, (int)(MROWS / 128)), dim3(256), 0, stream>>>(
        xb, wqkvt + (size_t)E_DIM * E_DIM, b_qkv + E_DIM, qkvb + E_DIM,
        (int)MROWS, 2 * D_HEAD, QKV_LD, E_DIM);

    v_transpose<<<dim3(MROWS_T / 32, D_HEAD / 32), dim3(32, 8), 0, stream>>>(qkvb, vtg);

    attn_kernel<<<dim3(B_SZ * H_NUM, 16), dim3(256), 0, stream>>>(qkvb, vtg, attnb);

    gemm256<false, false><<<dim3(E_DIM / 256, (int)(MROWS / 256)), dim3(512), 0, stream>>>(
        attnb, wfct, b_fc, out, (int)MROWS, E_DIM, E_DIM, E_DIM);
}

// Round 7
// 422.184 us; speedup vs baseline: 1.5247x; 1.5247x over previous
//
#include <hip/hip_runtime.h>

#define E_DIM 2048
#define H_NUM 16
#define D_HEAD 128
#define B_SZ 4
#define N_SEQ 2048
#define QKV_LD 2304   // E + 2*D
#define MROWS_T (B_SZ * N_SEQ)   // 8192
#define SC2F 0.12751744802582937f  // log2(e)/sqrt(128)

typedef __attribute__((ext_vector_type(8))) __bf16 bfx8;
typedef __attribute__((ext_vector_type(8))) short sx8;
typedef __attribute__((ext_vector_type(4))) short sx4;
typedef __attribute__((ext_vector_type(2))) short sx2;
typedef __attribute__((ext_vector_type(4))) int ix4;
typedef __attribute__((ext_vector_type(4))) float fx4;

__device__ __forceinline__ fx4 mfma_bf16(bfx8 a, bfx8 b, fx4 c) {
    return __builtin_amdgcn_mfma_f32_16x16x32_bf16(a, b, c, 0, 0, 0);
}

// fp32 -> bf16 round-to-nearest-even (finite inputs only)
__device__ __forceinline__ short f2bf(float f) {
    unsigned u = __builtin_bit_cast(unsigned, f);
    u += 0x7FFFu + ((u >> 16) & 1u);
    return (short)(u >> 16);
}

// pack two fp32 -> one dword of two bf16 (lo=a, hi=b)
__device__ __forceinline__ int cvt_pk_bf16(float a, float b) {
    int r;
    asm("v_cvt_pk_bf16_f32 %0, %1, %2" : "=v"(r) : "v"(a), "v"(b));
    return r;
}

__device__ __forceinline__ void gld_lds16(const void* g, void* l) {
    __builtin_amdgcn_global_load_lds((__attribute__((address_space(1))) void*)(void*)g,
                                     (__attribute__((address_space(3))) void*)l, 16, 0, 0);
}

// ---------------- cast fp32 -> bf16 (elementwise) ----------------
__global__ __launch_bounds__(256) void cast_f32_bf16(const float* __restrict__ in,
                                                     short* __restrict__ out, int n) {
    int i = (blockIdx.x * 256 + threadIdx.x) * 4;
    if (i >= n) return;
    float4 v = *(const float4*)(in + i);
    sx4 r = {f2bf(v.x), f2bf(v.y), f2bf(v.z), f2bf(v.w)};
    *(sx4*)(out + i) = r;
}

// ---------------- transpose + cast: in[R][C] fp32 -> out[C][R] bf16 ----------------
__global__ __launch_bounds__(256) void transpose_cast(const float* __restrict__ in,
                                                      short* __restrict__ out, int R, int C) {
    __shared__ float tile[32][33];
    int c0 = blockIdx.x * 32, r0 = blockIdx.y * 32;
    int tx = threadIdx.x;
    for (int i = threadIdx.y; i < 32; i += 8)
        tile[i][tx] = in[(size_t)(r0 + i) * C + c0 + tx];
    __syncthreads();
    for (int i = threadIdx.y; i < 32; i += 8)
        out[(size_t)(c0 + i) * R + r0 + tx] = f2bf(tile[tx][i]);
}

// ---------------- transpose V slice of qkv -> vtg[128][8192] bf16 ----------------
// Key axis stored PERMUTED within each 32-key group: position 2i <- key i,
// position 2i+1 <- key 16+i. With swapped QK^T this is exactly the A-operand k-axis
// order produced by cvt_pk(e_half0, e_half1) per quad: p = 8q+2j+h <-> key 16h+4q+j.
__global__ __launch_bounds__(256) void v_transpose(const short* __restrict__ qkv,
                                                   short* __restrict__ vtg) {
    __shared__ short tile[32][33];
    int r0 = blockIdx.x * 32;
    int d0 = blockIdx.y * 32;
    int tx = threadIdx.x;
    for (int i = threadIdx.y; i < 32; i += 8)
        tile[i][tx] = qkv[(size_t)(r0 + i) * QKV_LD + (E_DIM + D_HEAD) + d0 + tx];
    __syncthreads();
    int kp = ((tx & 15) << 1) | (tx >> 4);   // key-interleave permutation
    for (int i = threadIdx.y; i < 32; i += 8)
        vtg[(size_t)(d0 + i) * MROWS_T + r0 + kp] = tile[tx][i];
}

// ---------------- 128x128 GEMM (m97-structure) — used only for the small K/V slice ----------------
template <bool OUT_BF16, bool SCALE_Q>
__global__ __launch_bounds__(256) void gemm_bt(const short* __restrict__ A,
                                               const short* __restrict__ Bt,
                                               const float* __restrict__ bias,
                                               void* __restrict__ Cp,
                                               int M, int N, int ldc, int K) {
    __shared__ __align__(16) short As[128 * 32];
    __shared__ __align__(16) short Bs[128 * 32];
    const int tid = threadIdx.x, wave = tid >> 6, lane = tid & 63;
    const int quad = lane >> 4, l16 = lane & 15;

    const int gx = gridDim.x;
    int wg = blockIdx.y * gx + blockIdx.x;
    {
        const int nwg = gx * gridDim.y;
        const int qd = nwg >> 3, rm = nwg & 7;
        const int xcd = wg & 7, loc = wg >> 3;
        wg = (xcd < rm ? xcd * (qd + 1) : rm * (qd + 1) + (xcd - rm) * qd) + loc;
    }
    const int m0 = (wg / gx) * 128, n0 = (wg % gx) * 128;

    const int wm = (wave >> 1) * 64, wn = (wave & 1) * 64;
    const int srow = lane >> 2, scol = (lane & 3) * 8;

    fx4 acc[4][4];
#pragma unroll
    for (int mt = 0; mt < 4; ++mt)
#pragma unroll
        for (int nt = 0; nt < 4; ++nt) acc[mt][nt] = (fx4){0.f, 0.f, 0.f, 0.f};

    const short* Ag = A + (size_t)m0 * K;
    const short* Bg = Bt + (size_t)n0 * K;

    for (int k0 = 0; k0 < K; k0 += 32) {
#pragma unroll
        for (int i = 0; i < 2; ++i) {
            int chunk = wave * 2 + i;
            int row = chunk * 16 + srow;
            gld_lds16(Ag + (size_t)row * K + k0 + scol, &As[chunk * 512]);
            gld_lds16(Bg + (size_t)row * K + k0 + scol, &Bs[chunk * 512]);
        }
        __syncthreads();
        bfx8 af[4], bfr[4];
#pragma unroll
        for (int t = 0; t < 4; ++t) {
            af[t]  = *(const bfx8*)&As[(wm + t * 16 + l16) * 32 + quad * 8];
            bfr[t] = *(const bfx8*)&Bs[(wn + t * 16 + l16) * 32 + quad * 8];
        }
#pragma unroll
        for (int mt = 0; mt < 4; ++mt)
#pragma unroll
            for (int nt = 0; nt < 4; ++nt)
                acc[mt][nt] = mfma_bf16(af[mt], bfr[nt], acc[mt][nt]);
        __syncthreads();
    }

    const float scl = (SCALE_Q && n0 < E_DIM) ? SC2F : 1.0f;
    float bv[4];
#pragma unroll
    for (int nt = 0; nt < 4; ++nt) bv[nt] = bias[n0 + wn + nt * 16 + l16];

#pragma unroll
    for (int mt = 0; mt < 4; ++mt)
#pragma unroll
        for (int nt = 0; nt < 4; ++nt)
#pragma unroll
            for (int j = 0; j < 4; ++j) {
                int row = m0 + wm + mt * 16 + quad * 4 + j;
                int col = n0 + wn + nt * 16 + l16;
                float v = (acc[mt][nt][j] + bv[nt]) * scl;
                if (OUT_BF16)
                    ((short*)Cp)[(size_t)row * ldc + col] = f2bf(v);
                else
                    ((float*)Cp)[(size_t)row * ldc + col] = v;
            }
}

// ---------------- 256x256 8-phase GEMM (T2+T3+T4+T5), BK=64, 512 threads ----------------
// ROUND-2 SCHEDULE (harness-verified): phase's MFMA operands loaded in the same phase's
// mem region. Stage targets per tile t:
//   p0 -> (t+1).A.k1   p1 -> (t+1).B.k1   p2 -> (t+2).A.k0   p3 -> (t+2).B.k0
// One vmcnt(4) per tile (end of p3) guarantees the next tile's halves; vmcnt(0) at tails.
// Raw s_barrier (NOT __syncthreads -> would drain vmcnt); sched_barrier(0) fences phases.
// LDS swizzle: 16B-slot ^= (row>>1)&3 (write side via pre-swizzled global source).
template <bool OUT_BF16, bool SCALE_ALL>
__global__ __launch_bounds__(512) void gemm256(const short* __restrict__ A,
                                               const short* __restrict__ Bt,
                                               const float* __restrict__ bias,
                                               void* __restrict__ Cp,
                                               int M, int N, int ldc, int K) {
    __shared__ __align__(16) short lds[2][2][2][8192];   // [buf][kk][A=0/B=1][256*32]
    const int tid = threadIdx.x, wave = tid >> 6, lane = tid & 63;
    const int quad = lane >> 4, l16 = lane & 15;
    const int wmi = wave >> 2, wni = wave & 3;   // 2M x 4N wave grid
    const int m0 = blockIdx.y * 256, n0 = blockIdx.x * 256;

    const size_t rstep = (size_t)128 * K;
    const int srow = wave * 16 + (lane >> 2);
    const int sslot = (lane & 3) ^ ((lane >> 3) & 3);
    const short* Asrc = A + ((size_t)(m0 + srow)) * K + sslot * 8;
    const short* Bsrc = Bt + ((size_t)(n0 + srow)) * K + sslot * 8;

    auto stage = [&](const short* srcb, short* dstb, int kcol0) {
        gld_lds16(srcb + kcol0, dstb + wave * 512);
        gld_lds16(srcb + kcol0 + rstep, dstb + 4096 + wave * 512);
    };

    // fragment read offsets (swizzled): 16B-slot ^= (row>>1)&3
    const int swl = (l16 >> 1) & 3;
    const int aoff = (wmi * 128 + l16) * 32 + (quad ^ swl) * 8;
    const int boff = (wni * 64 + l16) * 32 + (quad ^ swl) * 8;

    fx4 acc[8][4];
#pragma unroll
    for (int m = 0; m < 8; ++m)
#pragma unroll
        for (int n = 0; n < 4; ++n) acc[m][n] = (fx4){0.f, 0.f, 0.f, 0.f};

    const int nt = K >> 6;

    // prologue: tile0 all 4 halves + tile1 k0; allow newest 2 halves outstanding
    stage(Asrc, &lds[0][0][0][0], 0);
    stage(Bsrc, &lds[0][0][1][0], 0);
    stage(Asrc, &lds[0][1][0][0], 32);
    stage(Bsrc, &lds[0][1][1][0], 32);
    stage(Asrc, &lds[1][0][0][0], 64);
    stage(Bsrc, &lds[1][0][1][0], 64);
    asm volatile("s_waitcnt vmcnt(4)");
    __builtin_amdgcn_s_barrier();
    __builtin_amdgcn_sched_barrier(0);

#pragma unroll 1
    for (int t = 0; t < nt; ++t) {
        const int cur = t & 1, nxt = cur ^ 1;
        const short* Ah0 = &lds[cur][0][0][0];
        const short* Bh0 = &lds[cur][0][1][0];
        const short* Ah1 = &lds[cur][1][0][0];
        const short* Bh1 = &lds[cur][1][1][0];
        const int kc = t * 64;
        bfx8 af[4], bf0[4], bf1[4];

        // ---- phase 0: kk=0, m 0-3 ----
#pragma unroll
        for (int n = 0; n < 4; ++n) bf0[n] = *(const bfx8*)&Bh0[boff + n * 512];
#pragma unroll
        for (int m = 0; m < 4; ++m) af[m] = *(const bfx8*)&Ah0[aoff + m * 512];
        if (t + 1 < nt) stage(Asrc, &lds[nxt][1][0][0], kc + 96);
        __builtin_amdgcn_s_barrier();
        __builtin_amdgcn_sched_barrier(0);
        __builtin_amdgcn_s_setprio(1);
#pragma unroll
        for (int m = 0; m < 4; ++m)
#pragma unroll
            for (int n = 0; n < 4; ++n) acc[m][n] = mfma_bf16(af[m], bf0[n], acc[m][n]);
        __builtin_amdgcn_s_setprio(0);
        __builtin_amdgcn_s_barrier();
        __builtin_amdgcn_sched_barrier(0);

        // ---- phase 1: kk=0, m 4-7 ----
#pragma unroll
        for (int m = 0; m < 4; ++m) af[m] = *(const bfx8*)&Ah0[aoff + (m + 4) * 512];
        if (t + 1 < nt) stage(Bsrc, &lds[nxt][1][1][0], kc + 96);
        __builtin_amdgcn_s_barrier();
        __builtin_amdgcn_sched_barrier(0);
        __builtin_amdgcn_s_setprio(1);
#pragma unroll
        for (int m = 0; m < 4; ++m)
#pragma unroll
            for (int n = 0; n < 4; ++n) acc[m + 4][n] = mfma_bf16(af[m], bf0[n], acc[m + 4][n]);
        __builtin_amdgcn_s_setprio(0);
        __builtin_amdgcn_s_barrier();
        __builtin_amdgcn_sched_barrier(0);

        // ---- phase 2: kk=1, m 0-3 ----
#pragma unroll
        for (int n = 0; n < 4; ++n) bf1[n] = *(const bfx8*)&Bh1[boff + n * 512];
#pragma unroll
        for (int m = 0; m < 4; ++m) af[m] = *(const bfx8*)&Ah1[aoff + m * 512];
        if (t + 2 < nt) stage(Asrc, &lds[cur][0][0][0], kc + 128);
        __builtin_amdgcn_s_barrier();
        __builtin_amdgcn_sched_barrier(0);
        __builtin_amdgcn_s_setprio(1);
#pragma unroll
        for (int m = 0; m < 4; ++m)
#pragma unroll
            for (int n = 0; n < 4; ++n) acc[m][n] = mfma_bf16(af[m], bf1[n], acc[m][n]);
        __builtin_amdgcn_s_setprio(0);
        __builtin_amdgcn_s_barrier();
        __builtin_amdgcn_sched_barrier(0);

        // ---- phase 3: kk=1, m 4-7 ----
#pragma unroll
        for (int m = 0; m < 4; ++m) af[m] = *(const bfx8*)&Ah1[aoff + (m + 4) * 512];
        if (t + 2 < nt) stage(Bsrc, &lds[cur][0][1][0], kc + 128);
        __builtin_amdgcn_s_barrier();
        __builtin_amdgcn_sched_barrier(0);
        __builtin_amdgcn_s_setprio(1);
#pragma unroll
        for (int m = 0; m < 4; ++m)
#pragma unroll
            for (int n = 0; n < 4; ++n) acc[m + 4][n] = mfma_bf16(af[m], bf1[n], acc[m + 4][n]);
        __builtin_amdgcn_s_setprio(0);
        if (t < nt - 2) asm volatile("s_waitcnt vmcnt(4)");
        else            asm volatile("s_waitcnt vmcnt(0)");
        __builtin_amdgcn_s_barrier();
        __builtin_amdgcn_sched_barrier(0);
    }

    const float scl = SCALE_ALL ? SC2F : 1.0f;
    float bvn[4];
#pragma unroll
    for (int n = 0; n < 4; ++n) bvn[n] = bias[n0 + wni * 64 + n * 16 + l16];

#pragma unroll
    for (int m = 0; m < 8; ++m)
#pragma unroll
        for (int n = 0; n < 4; ++n)
#pragma unroll
            for (int j = 0; j < 4; ++j) {
                int row = m0 + wmi * 128 + m * 16 + quad * 4 + j;
                int col = n0 + wni * 64 + n * 16 + l16;
                float v = (acc[m][n][j] + bvn[n]) * scl;
                if (OUT_BF16)
                    ((short*)Cp)[(size_t)row * ldc + col] = f2bf(v);
                else
                    ((float*)Cp)[(size_t)row * ldc + col] = v;
            }
}

// ---------------- Flash attention (multi-query, causal) ----------------
// Round-5 paired structure (grid 8 x 64, halves (bx, 15-bx) -> uniform 68 tiles;
// co-scheduled same-(b,h) blocks = the L2 strategy, round-6 lesson).
// SWAPPED QK^T (T12): s = mfma(K, Q) -> lane l16 holds P[q=l16][keys quad*4+j] for
// both 16-key halves. cvt_pk(e_h0[j], e_h1[j]) builds the PV A-fragment DIRECTLY in
// registers under the k-axis permutation p=8q+2j+h <-> key 16h+4q+j, which is exactly
// vtg's stored key order -> the P-tile LDS round-trip is gone entirely.
// l-denominator lives at lane l16 (per q-row); fetched per-j with one __shfl at the end.
// K/V LDS: involution slot-swizzle sigma(s)=s^((s>>3)&7) on 16B slots (conflict-free
// ds_read_b128); V fragments hoisted before the softmax to overlap DS latency.
__global__ __launch_bounds__(256, 2) void attn_kernel(const short* __restrict__ qkv,
                                                      const short* __restrict__ vtg,
                                                      short* __restrict__ outp) {
    __shared__ __align__(16) short Ks[2][4096];
    __shared__ __align__(16) short Vt[2][4096];
    const int b = blockIdx.y >> 4, h = blockIdx.y & 15;
    const int tid = threadIdx.x, wave = tid >> 6, lane = tid & 63;
    const int quad = lane >> 4, l16 = lane & 15;
    const size_t baseRow = (size_t)b * N_SEQ;

    // staging: lane l fetches logical slot sigma(l) = l ^ ((l>>3)&7)
    const int sl = lane ^ ((lane >> 3) & 7);
    const int srow = sl >> 2, sq = sl & 3;
    // read: logical slot (l16*4+quad) lives at physical slot ^ ((l16>>1)&7)
    const int rslot = ((l16 * 4 + quad) ^ ((l16 >> 1) & 7)) * 8;

    auto stage = [&](int k0, int bufi) {
#pragma unroll
        for (int i = 0; i < 2; ++i) {
            const int c = wave * 2 + i;
            gld_lds16(qkv + (baseRow + k0 + (c & 1) * 16 + srow) * QKV_LD + E_DIM +
                          (c >> 1) * 32 + sq * 8,
                      &Ks[bufi][c * 512]);
            gld_lds16(vtg + (size_t)(c * 16 + srow) * MROWS_T + baseRow + k0 + sq * 8,
                      &Vt[bufi][c * 512]);
        }
    };

#pragma unroll 1
    for (int half = 0; half < 2; ++half) {
        const int chunk = half ? (15 - blockIdx.x) : blockIdx.x;
        const int q0 = chunk * 128;
        const int wrow = q0 + wave * 32;

        bfx8 aq0[4], aq1[4];
        {
            const short* qb0 = qkv + (baseRow + wrow + l16) * QKV_LD + h * D_HEAD + quad * 8;
            const short* qb1 = qb0 + 16 * QKV_LD;
#pragma unroll
            for (int c = 0; c < 4; ++c) {
                aq0[c] = *(const bfx8*)(qb0 + c * 32);
                aq1[c] = *(const bfx8*)(qb1 + c * 32);
            }
        }

        fx4 accO0[8], accO1[8];
        float l0 = 0.f, l1 = 0.f;
#pragma unroll
        for (int dt = 0; dt < 8; ++dt) {
            accO0[dt] = (fx4){0.f, 0.f, 0.f, 0.f};
            accO1[dt] = (fx4){0.f, 0.f, 0.f, 0.f};
        }

        const int nbulk = 4 * chunk;
        const int nkt = nbulk + 4;

        __syncthreads();   // all waves done reading LDS from previous half
        stage(0, 0);

#pragma unroll 1
        for (int kt = 0; kt < nkt; ++kt) {
            __syncthreads();   // buf[kt&1] ready (vmcnt drain hidden by previous compute)
            if (kt + 1 < nkt) stage((kt + 1) << 5, (kt + 1) & 1);
            const short* ks = Ks[kt & 1];
            const short* vs = Vt[kt & 1];
            const int k0 = kt << 5;

            // SWAPPED S^T = K Q^T: lane l16 holds P[q=l16][key = k0 + (half?16:0) + quad*4+j]
            fx4 s00 = {0.f, 0.f, 0.f, 0.f}, s01 = {0.f, 0.f, 0.f, 0.f};
            fx4 s10 = {0.f, 0.f, 0.f, 0.f}, s11 = {0.f, 0.f, 0.f, 0.f};
            __builtin_amdgcn_s_setprio(1);
#pragma unroll
            for (int dc = 0; dc < 4; ++dc) {
                bfx8 kf0 = *(const bfx8*)&ks[(dc * 2 + 0) * 512 + rslot];
                bfx8 kf1 = *(const bfx8*)&ks[(dc * 2 + 1) * 512 + rslot];
                s00 = mfma_bf16(kf0, aq0[dc], s00);
                s01 = mfma_bf16(kf1, aq0[dc], s01);
                s10 = mfma_bf16(kf0, aq1[dc], s10);
                s11 = mfma_bf16(kf1, aq1[dc], s11);
            }
            __builtin_amdgcn_s_setprio(0);

            // hoist V fragments: DS latency overlaps the softmax VALU below
            bfx8 bvr[8];
#pragma unroll
            for (int dt = 0; dt < 8; ++dt)
                bvr[dt] = *(const bfx8*)&vs[dt * 512 + rslot];

            const bool diag = kt >= nbulk;
            int pk0[4], pk1[4];
#pragma unroll
            for (int j = 0; j < 4; ++j) {
                float e0 = __builtin_amdgcn_exp2f(s00[j]);
                float e1 = __builtin_amdgcn_exp2f(s01[j]);
                if (diag) {
                    const int key = k0 + quad * 4 + j;
                    const int qr = wrow + l16;
                    e0 = (key <= qr) ? e0 : 0.f;
                    e1 = (key + 16 <= qr) ? e1 : 0.f;
                }
                l0 += e0 + e1;
                pk0[j] = cvt_pk_bf16(e0, e1);
            }
#pragma unroll
            for (int j = 0; j < 4; ++j) {
                float e0 = __builtin_amdgcn_exp2f(s10[j]);
                float e1 = __builtin_amdgcn_exp2f(s11[j]);
                if (diag) {
                    const int key = k0 + quad * 4 + j;
                    const int qr = wrow + 16 + l16;
                    e0 = (key <= qr) ? e0 : 0.f;
                    e1 = (key + 16 <= qr) ? e1 : 0.f;
                }
                l1 += e0 + e1;
                pk1[j] = cvt_pk_bf16(e0, e1);
            }

            bfx8 ap0 = __builtin_bit_cast(bfx8, (ix4){pk0[0], pk0[1], pk0[2], pk0[3]});
            bfx8 ap1 = __builtin_bit_cast(bfx8, (ix4){pk1[0], pk1[1], pk1[2], pk1[3]});
            __builtin_amdgcn_s_setprio(1);
#pragma unroll
            for (int dt = 0; dt < 8; ++dt) {
                accO0[dt] = mfma_bf16(ap0, bvr[dt], accO0[dt]);
                accO1[dt] = mfma_bf16(ap1, bvr[dt], accO1[dt]);
            }
            __builtin_amdgcn_s_setprio(0);
        }

        // l currently per-lane partial over this quad's keys; reduce across quads
        // (lane bits 4,5) -> every lane holds L[q = wrow (+16) + l16]
        l0 += __shfl_xor(l0, 16); l0 += __shfl_xor(l0, 32);
        l1 += __shfl_xor(l1, 16); l1 += __shfl_xor(l1, 32);

#pragma unroll
        for (int j = 0; j < 4; ++j) {
            // output row q = wrow + quad*4 + j; its L lives at lane l16 = quad*4+j
            float rl0 = 1.0f / __shfl(l0, quad * 4 + j);
            float rl1 = 1.0f / __shfl(l1, quad * 4 + j);
            size_t ob0 = (baseRow + wrow + quad * 4 + j) * (size_t)E_DIM + h * D_HEAD + l16;
            size_t ob1 = ob0 + (size_t)16 * E_DIM;
#pragma unroll
            for (int dt = 0; dt < 8; ++dt) {
                outp[ob0 + dt * 16] = f2bf(accO0[dt][j] * rl0);
                outp[ob1 + dt * 16] = f2bf(accO1[dt][j] * rl1);
            }
        }
    }
}

extern "C" void kernel_launch(void* const* d_in, const int* in_sizes, int n_in,
                              void* d_out, int out_size, void* d_ws, size_t ws_size,
                              hipStream_t stream) {
    const float* x     = (const float*)d_in[0];
    const float* w_qkv = (const float*)d_in[1];
    const float* b_qkv = (const float*)d_in[2];
    const float* w_fc  = (const float*)d_in[3];
    const float* b_fc  = (const float*)d_in[4];
    float* out = (float*)d_out;

    const size_t MROWS = (size_t)B_SZ * N_SEQ;  // 8192
    short* xb    = (short*)d_ws;                         // 8192*2048
    short* wqkvt = xb + MROWS * E_DIM;                   // 2304*2048
    short* wfct  = wqkvt + (size_t)QKV_LD * E_DIM;       // 2048*2048
    short* qkvb  = wfct + (size_t)E_DIM * E_DIM;         // 8192*2304
    short* attnb = qkvb + MROWS * QKV_LD;                // 8192*2048
    short* vtg   = xb;   // reuse: xb dead after QKV GEMM

    cast_f32_bf16<<<dim3((int)(MROWS * E_DIM / 1024)), dim3(256), 0, stream>>>(
        x, xb, (int)(MROWS * E_DIM));
    transpose_cast<<<dim3(QKV_LD / 32, E_DIM / 32), dim3(32, 8), 0, stream>>>(
        w_qkv, wqkvt, E_DIM, QKV_LD);
    transpose_cast<<<dim3(E_DIM / 32, E_DIM / 32), dim3(32, 8), 0, stream>>>(
        w_fc, wfct, E_DIM, E_DIM);

    // QKV projection, Q columns (0..2047), scaled by SC2F: 256-grid, one clean round
    gemm256<true, true><<<dim3(E_DIM / 256, (int)(MROWS / 256)), dim3(512), 0, stream>>>(
        xb, wqkvt, b_qkv, qkvb, (int)MROWS, E_DIM, QKV_LD, E_DIM);
    // K/V columns (2048..2303), unscaled: small 128-block 128^2 dispatch
    gemm_bt<true, false><<<dim3(2, (int)(MROWS / 128)), dim3(256), 0, stream>>>(
        xb, wqkvt + (size_t)E_DIM * E_DIM, b_qkv + E_DIM, qkvb + E_DIM,
        (int)MROWS, 2 * D_HEAD, QKV_LD, E_DIM);

    v_transpose<<<dim3(MROWS_T / 32, D_HEAD / 32), dim3(32, 8), 0, stream>>>(qkvb, vtg);

    attn_kernel<<<dim3(8, B_SZ * H_NUM), dim3(256), 0, stream>>>(qkvb, vtg, attnb);

    gemm256<false, false><<<dim3(E_DIM / 256, (int)(MROWS / 256)), dim3(512), 0, stream>>>(
        attnb, wfct, b_fc, out, (int)MROWS, E_DIM, E_DIM, E_DIM);
}

// Round 9
// 419.829 us; speedup vs baseline: 1.5333x; 1.0056x over previous
//
#include <hip/hip_runtime.h>

#define E_DIM 2048
#define H_NUM 16
#define D_HEAD 128
#define B_SZ 4
#define N_SEQ 2048
#define QKV_LD 2304   // E + 2*D
#define MROWS_T (B_SZ * N_SEQ)   // 8192
#define SC2F 0.12751744802582937f  // log2(e)/sqrt(128)

typedef __attribute__((ext_vector_type(8))) __bf16 bfx8;
typedef __attribute__((ext_vector_type(8))) short sx8;
typedef __attribute__((ext_vector_type(4))) short sx4;
typedef __attribute__((ext_vector_type(2))) short sx2;
typedef __attribute__((ext_vector_type(4))) int ix4;
typedef __attribute__((ext_vector_type(4))) float fx4;

__device__ __forceinline__ fx4 mfma_bf16(bfx8 a, bfx8 b, fx4 c) {
    return __builtin_amdgcn_mfma_f32_16x16x32_bf16(a, b, c, 0, 0, 0);
}

// fp32 -> bf16 round-to-nearest-even (finite inputs only)
__device__ __forceinline__ short f2bf(float f) {
    unsigned u = __builtin_bit_cast(unsigned, f);
    u += 0x7FFFu + ((u >> 16) & 1u);
    return (short)(u >> 16);
}

// pack two fp32 -> one dword of two bf16 (lo=a, hi=b)
__device__ __forceinline__ int cvt_pk_bf16(float a, float b) {
    int r;
    asm("v_cvt_pk_bf16_f32 %0, %1, %2" : "=v"(r) : "v"(a), "v"(b));
    return r;
}

__device__ __forceinline__ void gld_lds16(const void* g, void* l) {
    __builtin_amdgcn_global_load_lds((__attribute__((address_space(1))) void*)(void*)g,
                                     (__attribute__((address_space(3))) void*)l, 16, 0, 0);
}

// ---------------- cast fp32 -> bf16 (elementwise) ----------------
__global__ __launch_bounds__(256) void cast_f32_bf16(const float* __restrict__ in,
                                                     short* __restrict__ out, int n) {
    int i = (blockIdx.x * 256 + threadIdx.x) * 4;
    if (i >= n) return;
    float4 v = *(const float4*)(in + i);
    sx4 r = {f2bf(v.x), f2bf(v.y), f2bf(v.z), f2bf(v.w)};
    *(sx4*)(out + i) = r;
}

// ---------------- transpose + cast: in[R][C] fp32 -> out[C][R] bf16 ----------------
__global__ __launch_bounds__(256) void transpose_cast(const float* __restrict__ in,
                                                      short* __restrict__ out, int R, int C) {
    __shared__ float tile[32][33];
    int c0 = blockIdx.x * 32, r0 = blockIdx.y * 32;
    int tx = threadIdx.x;
    for (int i = threadIdx.y; i < 32; i += 8)
        tile[i][tx] = in[(size_t)(r0 + i) * C + c0 + tx];
    __syncthreads();
    for (int i = threadIdx.y; i < 32; i += 8)
        out[(size_t)(c0 + i) * R + r0 + tx] = f2bf(tile[tx][i]);
}

// ---------------- transpose V slice of qkv -> vtg[128][8192] bf16 ----------------
// Key axis stored PERMUTED within each 32-key group: position 2i <- key i,
// position 2i+1 <- key 16+i. With swapped QK^T this is exactly the A-operand k-axis
// order produced by cvt_pk(e_half0, e_half1) per quad: p = 8q+2j+h <-> key 16h+4q+j.
__global__ __launch_bounds__(256) void v_transpose(const short* __restrict__ qkv,
                                                   short* __restrict__ vtg) {
    __shared__ short tile[32][33];
    int r0 = blockIdx.x * 32;
    int d0 = blockIdx.y * 32;
    int tx = threadIdx.x;
    for (int i = threadIdx.y; i < 32; i += 8)
        tile[i][tx] = qkv[(size_t)(r0 + i) * QKV_LD + (E_DIM + D_HEAD) + d0 + tx];
    __syncthreads();
    int kp = ((tx & 15) << 1) | (tx >> 4);   // key-interleave permutation
    for (int i = threadIdx.y; i < 32; i += 8)
        vtg[(size_t)(d0 + i) * MROWS_T + r0 + kp] = tile[tx][i];
}

// ---------------- 128x128 GEMM (m97-structure) — used only for the small K/V slice ----------------
template <bool OUT_BF16, bool SCALE_Q>
__global__ __launch_bounds__(256) void gemm_bt(const short* __restrict__ A,
                                               const short* __restrict__ Bt,
                                               const float* __restrict__ bias,
                                               void* __restrict__ Cp,
                                               int M, int N, int ldc, int K) {
    __shared__ __align__(16) short As[128 * 32];
    __shared__ __align__(16) short Bs[128 * 32];
    const int tid = threadIdx.x, wave = tid >> 6, lane = tid & 63;
    const int quad = lane >> 4, l16 = lane & 15;

    const int gx = gridDim.x;
    int wg = blockIdx.y * gx + blockIdx.x;
    {
        const int nwg = gx * gridDim.y;
        const int qd = nwg >> 3, rm = nwg & 7;
        const int xcd = wg & 7, loc = wg >> 3;
        wg = (xcd < rm ? xcd * (qd + 1) : rm * (qd + 1) + (xcd - rm) * qd) + loc;
    }
    const int m0 = (wg / gx) * 128, n0 = (wg % gx) * 128;

    const int wm = (wave >> 1) * 64, wn = (wave & 1) * 64;
    const int srow = lane >> 2, scol = (lane & 3) * 8;

    fx4 acc[4][4];
#pragma unroll
    for (int mt = 0; mt < 4; ++mt)
#pragma unroll
        for (int nt = 0; nt < 4; ++nt) acc[mt][nt] = (fx4){0.f, 0.f, 0.f, 0.f};

    const short* Ag = A + (size_t)m0 * K;
    const short* Bg = Bt + (size_t)n0 * K;

    for (int k0 = 0; k0 < K; k0 += 32) {
#pragma unroll
        for (int i = 0; i < 2; ++i) {
            int chunk = wave * 2 + i;
            int row = chunk * 16 + srow;
            gld_lds16(Ag + (size_t)row * K + k0 + scol, &As[chunk * 512]);
            gld_lds16(Bg + (size_t)row * K + k0 + scol, &Bs[chunk * 512]);
        }
        __syncthreads();
        bfx8 af[4], bfr[4];
#pragma unroll
        for (int t = 0; t < 4; ++t) {
            af[t]  = *(const bfx8*)&As[(wm + t * 16 + l16) * 32 + quad * 8];
            bfr[t] = *(const bfx8*)&Bs[(wn + t * 16 + l16) * 32 + quad * 8];
        }
#pragma unroll
        for (int mt = 0; mt < 4; ++mt)
#pragma unroll
            for (int nt = 0; nt < 4; ++nt)
                acc[mt][nt] = mfma_bf16(af[mt], bfr[nt], acc[mt][nt]);
        __syncthreads();
    }

    const float scl = (SCALE_Q && n0 < E_DIM) ? SC2F : 1.0f;
    float bv[4];
#pragma unroll
    for (int nt = 0; nt < 4; ++nt) bv[nt] = bias[n0 + wn + nt * 16 + l16];

#pragma unroll
    for (int mt = 0; mt < 4; ++mt)
#pragma unroll
        for (int nt = 0; nt < 4; ++nt)
#pragma unroll
            for (int j = 0; j < 4; ++j) {
                int row = m0 + wm + mt * 16 + quad * 4 + j;
                int col = n0 + wn + nt * 16 + l16;
                float v = (acc[mt][nt][j] + bv[nt]) * scl;
                if (OUT_BF16)
                    ((short*)Cp)[(size_t)row * ldc + col] = f2bf(v);
                else
                    ((float*)Cp)[(size_t)row * ldc + col] = v;
            }
}

// ---------------- 256x256 8-phase GEMM (T2+T3+T4+T5), BK=64, 512 threads ----------------
// ROUND-2 SCHEDULE (harness-verified): phase's MFMA operands loaded in the same phase's
// mem region. Stage targets per tile t:
//   p0 -> (t+1).A.k1   p1 -> (t+1).B.k1   p2 -> (t+2).A.k0   p3 -> (t+2).B.k0
// One vmcnt(4) per tile (end of p3) guarantees the next tile's halves; vmcnt(0) at tails.
// Raw s_barrier (NOT __syncthreads -> would drain vmcnt); sched_barrier(0) fences phases.
// LDS swizzle: 16B-slot ^= (row>>1)&3 (write side via pre-swizzled global source).
// NEW (T1/m204): bijective XCD block swizzle — each XCD gets a contiguous logical chunk
// (4 A-panels + B, ~12MB; A-panels ~4MB = L2-resident) instead of all 32 A-panels.
template <bool OUT_BF16, bool SCALE_ALL>
__global__ __launch_bounds__(512) void gemm256(const short* __restrict__ A,
                                               const short* __restrict__ Bt,
                                               const float* __restrict__ bias,
                                               void* __restrict__ Cp,
                                               int M, int N, int ldc, int K) {
    __shared__ __align__(16) short lds[2][2][2][8192];   // [buf][kk][A=0/B=1][256*32]
    const int tid = threadIdx.x, wave = tid >> 6, lane = tid & 63;
    const int quad = lane >> 4, l16 = lane & 15;
    const int wmi = wave >> 2, wni = wave & 3;   // 2M x 4N wave grid

    const int gx = gridDim.x;
    int wg = blockIdx.y * gx + blockIdx.x;
    {
        const int nwg = gx * gridDim.y;
        const int qd = nwg >> 3, rm = nwg & 7;
        const int xcd = wg & 7, loc = wg >> 3;
        wg = (xcd < rm ? xcd * (qd + 1) : rm * (qd + 1) + (xcd - rm) * qd) + loc;
    }
    const int m0 = (wg / gx) * 256, n0 = (wg % gx) * 256;

    const size_t rstep = (size_t)128 * K;
    const int srow = wave * 16 + (lane >> 2);
    const int sslot = (lane & 3) ^ ((lane >> 3) & 3);
    const short* Asrc = A + ((size_t)(m0 + srow)) * K + sslot * 8;
    const short* Bsrc = Bt + ((size_t)(n0 + srow)) * K + sslot * 8;

    auto stage = [&](const short* srcb, short* dstb, int kcol0) {
        gld_lds16(srcb + kcol0, dstb + wave * 512);
        gld_lds16(srcb + kcol0 + rstep, dstb + 4096 + wave * 512);
    };

    // fragment read offsets (swizzled): 16B-slot ^= (row>>1)&3
    const int swl = (l16 >> 1) & 3;
    const int aoff = (wmi * 128 + l16) * 32 + (quad ^ swl) * 8;
    const int boff = (wni * 64 + l16) * 32 + (quad ^ swl) * 8;

    fx4 acc[8][4];
#pragma unroll
    for (int m = 0; m < 8; ++m)
#pragma unroll
        for (int n = 0; n < 4; ++n) acc[m][n] = (fx4){0.f, 0.f, 0.f, 0.f};

    const int nt = K >> 6;

    // prologue: tile0 all 4 halves + tile1 k0; allow newest 2 halves outstanding
    stage(Asrc, &lds[0][0][0][0], 0);
    stage(Bsrc, &lds[0][0][1][0], 0);
    stage(Asrc, &lds[0][1][0][0], 32);
    stage(Bsrc, &lds[0][1][1][0], 32);
    stage(Asrc, &lds[1][0][0][0], 64);
    stage(Bsrc, &lds[1][0][1][0], 64);
    asm volatile("s_waitcnt vmcnt(4)");
    __builtin_amdgcn_s_barrier();
    __builtin_amdgcn_sched_barrier(0);

#pragma unroll 1
    for (int t = 0; t < nt; ++t) {
        const int cur = t & 1, nxt = cur ^ 1;
        const short* Ah0 = &lds[cur][0][0][0];
        const short* Bh0 = &lds[cur][0][1][0];
        const short* Ah1 = &lds[cur][1][0][0];
        const short* Bh1 = &lds[cur][1][1][0];
        const int kc = t * 64;
        bfx8 af[4], bf0[4], bf1[4];

        // ---- phase 0: kk=0, m 0-3 ----
#pragma unroll
        for (int n = 0; n < 4; ++n) bf0[n] = *(const bfx8*)&Bh0[boff + n * 512];
#pragma unroll
        for (int m = 0; m < 4; ++m) af[m] = *(const bfx8*)&Ah0[aoff + m * 512];
        if (t + 1 < nt) stage(Asrc, &lds[nxt][1][0][0], kc + 96);
        __builtin_amdgcn_s_barrier();
        __builtin_amdgcn_sched_barrier(0);
        __builtin_amdgcn_s_setprio(1);
#pragma unroll
        for (int m = 0; m < 4; ++m)
#pragma unroll
            for (int n = 0; n < 4; ++n) acc[m][n] = mfma_bf16(af[m], bf0[n], acc[m][n]);
        __builtin_amdgcn_s_setprio(0);
        __builtin_amdgcn_s_barrier();
        __builtin_amdgcn_sched_barrier(0);

        // ---- phase 1: kk=0, m 4-7 ----
#pragma unroll
        for (int m = 0; m < 4; ++m) af[m] = *(const bfx8*)&Ah0[aoff + (m + 4) * 512];
        if (t + 1 < nt) stage(Bsrc, &lds[nxt][1][1][0], kc + 96);
        __builtin_amdgcn_s_barrier();
        __builtin_amdgcn_sched_barrier(0);
        __builtin_amdgcn_s_setprio(1);
#pragma unroll
        for (int m = 0; m < 4; ++m)
#pragma unroll
            for (int n = 0; n < 4; ++n) acc[m + 4][n] = mfma_bf16(af[m], bf0[n], acc[m + 4][n]);
        __builtin_amdgcn_s_setprio(0);
        __builtin_amdgcn_s_barrier();
        __builtin_amdgcn_sched_barrier(0);

        // ---- phase 2: kk=1, m 0-3 ----
#pragma unroll
        for (int n = 0; n < 4; ++n) bf1[n] = *(const bfx8*)&Bh1[boff + n * 512];
#pragma unroll
        for (int m = 0; m < 4; ++m) af[m] = *(const bfx8*)&Ah1[aoff + m * 512];
        if (t + 2 < nt) stage(Asrc, &lds[cur][0][0][0], kc + 128);
        __builtin_amdgcn_s_barrier();
        __builtin_amdgcn_sched_barrier(0);
        __builtin_amdgcn_s_setprio(1);
#pragma unroll
        for (int m = 0; m < 4; ++m)
#pragma unroll
            for (int n = 0; n < 4; ++n) acc[m][n] = mfma_bf16(af[m], bf1[n], acc[m][n]);
        __builtin_amdgcn_s_setprio(0);
        __builtin_amdgcn_s_barrier();
        __builtin_amdgcn_sched_barrier(0);

        // ---- phase 3: kk=1, m 4-7 ----
#pragma unroll
        for (int m = 0; m < 4; ++m) af[m] = *(const bfx8*)&Ah1[aoff + (m + 4) * 512];
        if (t + 2 < nt) stage(Bsrc, &lds[cur][0][1][0], kc + 128);
        __builtin_amdgcn_s_barrier();
        __builtin_amdgcn_sched_barrier(0);
        __builtin_amdgcn_s_setprio(1);
#pragma unroll
        for (int m = 0; m < 4; ++m)
#pragma unroll
            for (int n = 0; n < 4; ++n) acc[m + 4][n] = mfma_bf16(af[m], bf1[n], acc[m + 4][n]);
        __builtin_amdgcn_s_setprio(0);
        if (t < nt - 2) asm volatile("s_waitcnt vmcnt(4)");
        else            asm volatile("s_waitcnt vmcnt(0)");
        __builtin_amdgcn_s_barrier();
        __builtin_amdgcn_sched_barrier(0);
    }

    const float scl = SCALE_ALL ? SC2F : 1.0f;
    float bvn[4];
#pragma unroll
    for (int n = 0; n < 4; ++n) bvn[n] = bias[n0 + wni * 64 + n * 16 + l16];

#pragma unroll
    for (int m = 0; m < 8; ++m)
#pragma unroll
        for (int n = 0; n < 4; ++n)
#pragma unroll
            for (int j = 0; j < 4; ++j) {
                int row = m0 + wmi * 128 + m * 16 + quad * 4 + j;
                int col = n0 + wni * 64 + n * 16 + l16;
                float v = (acc[m][n][j] + bvn[n]) * scl;
                if (OUT_BF16)
                    ((short*)Cp)[(size_t)row * ldc + col] = f2bf(v);
                else
                    ((float*)Cp)[(size_t)row * ldc + col] = v;
            }
}

// ---------------- Flash attention (multi-query, causal) ----------------
// ROUND-7 VERIFIED SOURCE (97.7us, conflicts=0). Paired structure (grid 8 x 64, halves
// (bx, 15-bx) -> uniform 68 tiles; co-scheduled same-(b,h) blocks = the L2 strategy).
// SWAPPED QK^T (T12): s = mfma(K, Q) -> lane l16 holds P[q=l16][keys quad*4+j] for
// both 16-key halves. cvt_pk(e_h0[j], e_h1[j]) builds the PV A-fragment DIRECTLY in
// registers under the k-axis permutation p=8q+2j+h <-> key 16h+4q+j (= vtg's stored
// key order) -> no P-tile LDS round-trip. K/V LDS: involution slot-swizzle
// sigma(s)=s^((s>>3)&7) on 16B slots; V fragments hoisted before the softmax.
__global__ __launch_bounds__(256, 2) void attn_kernel(const short* __restrict__ qkv,
                                                      const short* __restrict__ vtg,
                                                      short* __restrict__ outp) {
    __shared__ __align__(16) short Ks[2][4096];
    __shared__ __align__(16) short Vt[2][4096];
    const int b = blockIdx.y >> 4, h = blockIdx.y & 15;
    const int tid = threadIdx.x, wave = tid >> 6, lane = tid & 63;
    const int quad = lane >> 4, l16 = lane & 15;
    const size_t baseRow = (size_t)b * N_SEQ;

    // staging: lane l fetches logical slot sigma(l) = l ^ ((l>>3)&7)
    const int sl = lane ^ ((lane >> 3) & 7);
    const int srow = sl >> 2, sq = sl & 3;
    // read: logical slot (l16*4+quad) lives at physical slot ^ ((l16>>1)&7)
    const int rslot = ((l16 * 4 + quad) ^ ((l16 >> 1) & 7)) * 8;

    auto stage = [&](int k0, int bufi) {
#pragma unroll
        for (int i = 0; i < 2; ++i) {
            const int c = wave * 2 + i;
            gld_lds16(qkv + (baseRow + k0 + (c & 1) * 16 + srow) * QKV_LD + E_DIM +
                          (c >> 1) * 32 + sq * 8,
                      &Ks[bufi][c * 512]);
            gld_lds16(vtg + (size_t)(c * 16 + srow) * MROWS_T + baseRow + k0 + sq * 8,
                      &Vt[bufi][c * 512]);
        }
    };

#pragma unroll 1
    for (int half = 0; half < 2; ++half) {
        const int chunk = half ? (15 - blockIdx.x) : blockIdx.x;
        const int q0 = chunk * 128;
        const int wrow = q0 + wave * 32;

        bfx8 aq0[4], aq1[4];
        {
            const short* qb0 = qkv + (baseRow + wrow + l16) * QKV_LD + h * D_HEAD + quad * 8;
            const short* qb1 = qb0 + 16 * QKV_LD;
#pragma unroll
            for (int c = 0; c < 4; ++c) {
                aq0[c] = *(const bfx8*)(qb0 + c * 32);
                aq1[c] = *(const bfx8*)(qb1 + c * 32);
            }
        }

        fx4 accO0[8], accO1[8];
        float l0 = 0.f, l1 = 0.f;
#pragma unroll
        for (int dt = 0; dt < 8; ++dt) {
            accO0[dt] = (fx4){0.f, 0.f, 0.f, 0.f};
            accO1[dt] = (fx4){0.f, 0.f, 0.f, 0.f};
        }

        const int nbulk = 4 * chunk;
        const int nkt = nbulk + 4;

        __syncthreads();   // all waves done reading LDS from previous half
        stage(0, 0);

#pragma unroll 1
        for (int kt = 0; kt < nkt; ++kt) {
            __syncthreads();   // buf[kt&1] ready (vmcnt drain hidden by previous compute)
            if (kt + 1 < nkt) stage((kt + 1) << 5, (kt + 1) & 1);
            const short* ks = Ks[kt & 1];
            const short* vs = Vt[kt & 1];
            const int k0 = kt << 5;

            // SWAPPED S^T = K Q^T: lane l16 holds P[q=l16][key = k0 + 16h + quad*4+j]
            fx4 s00 = {0.f, 0.f, 0.f, 0.f}, s01 = {0.f, 0.f, 0.f, 0.f};
            fx4 s10 = {0.f, 0.f, 0.f, 0.f}, s11 = {0.f, 0.f, 0.f, 0.f};
            __builtin_amdgcn_s_setprio(1);
#pragma unroll
            for (int dc = 0; dc < 4; ++dc) {
                bfx8 kf0 = *(const bfx8*)&ks[(dc * 2 + 0) * 512 + rslot];
                bfx8 kf1 = *(const bfx8*)&ks[(dc * 2 + 1) * 512 + rslot];
                s00 = mfma_bf16(kf0, aq0[dc], s00);
                s01 = mfma_bf16(kf1, aq0[dc], s01);
                s10 = mfma_bf16(kf0, aq1[dc], s10);
                s11 = mfma_bf16(kf1, aq1[dc], s11);
            }
            __builtin_amdgcn_s_setprio(0);

            // hoist V fragments: DS latency overlaps the softmax VALU below
            bfx8 bvr[8];
#pragma unroll
            for (int dt = 0; dt < 8; ++dt)
                bvr[dt] = *(const bfx8*)&vs[dt * 512 + rslot];

            const bool diag = kt >= nbulk;
            int pk0[4], pk1[4];
#pragma unroll
            for (int j = 0; j < 4; ++j) {
                float e0 = __builtin_amdgcn_exp2f(s00[j]);
                float e1 = __builtin_amdgcn_exp2f(s01[j]);
                if (diag) {
                    const int key = k0 + quad * 4 + j;
                    const int qr = wrow + l16;
                    e0 = (key <= qr) ? e0 : 0.f;
                    e1 = (key + 16 <= qr) ? e1 : 0.f;
                }
                l0 += e0 + e1;
                pk0[j] = cvt_pk_bf16(e0, e1);
            }
#pragma unroll
            for (int j = 0; j < 4; ++j) {
                float e0 = __builtin_amdgcn_exp2f(s10[j]);
                float e1 = __builtin_amdgcn_exp2f(s11[j]);
                if (diag) {
                    const int key = k0 + quad * 4 + j;
                    const int qr = wrow + 16 + l16;
                    e0 = (key <= qr) ? e0 : 0.f;
                    e1 = (key + 16 <= qr) ? e1 : 0.f;
                }
                l1 += e0 + e1;
                pk1[j] = cvt_pk_bf16(e0, e1);
            }

            bfx8 ap0 = __builtin_bit_cast(bfx8, (ix4){pk0[0], pk0[1], pk0[2], pk0[3]});
            bfx8 ap1 = __builtin_bit_cast(bfx8, (ix4){pk1[0], pk1[1], pk1[2], pk1[3]});
            __builtin_amdgcn_s_setprio(1);
#pragma unroll
            for (int dt = 0; dt < 8; ++dt) {
                accO0[dt] = mfma_bf16(ap0, bvr[dt], accO0[dt]);
                accO1[dt] = mfma_bf16(ap1, bvr[dt], accO1[dt]);
            }
            __builtin_amdgcn_s_setprio(0);
        }

        // l currently per-lane partial over this quad's keys; reduce across quads
        // (lane bits 4,5) -> every lane holds L[q = wrow (+16) + l16]
        l0 += __shfl_xor(l0, 16); l0 += __shfl_xor(l0, 32);
        l1 += __shfl_xor(l1, 16); l1 += __shfl_xor(l1, 32);

#pragma unroll
        for (int j = 0; j < 4; ++j) {
            // output row q = wrow + quad*4 + j; its L lives at lane l16 = quad*4+j
            float rl0 = 1.0f / __shfl(l0, quad * 4 + j);
            float rl1 = 1.0f / __shfl(l1, quad * 4 + j);
            size_t ob0 = (baseRow + wrow + quad * 4 + j) * (size_t)E_DIM + h * D_HEAD + l16;
            size_t ob1 = ob0 + (size_t)16 * E_DIM;
#pragma unroll
            for (int dt = 0; dt < 8; ++dt) {
                outp[ob0 + dt * 16] = f2bf(accO0[dt][j] * rl0);
                outp[ob1 + dt * 16] = f2bf(accO1[dt][j] * rl1);
            }
        }
    }
}

extern "C" void kernel_launch(void* const* d_in, const int* in_sizes, int n_in,
                              void* d_out, int out_size, void* d_ws, size_t ws_size,
                              hipStream_t stream) {
    const float* x     = (const float*)d_in[0];
    const float* w_qkv = (const float*)d_in[1];
    const float* b_qkv = (const float*)d_in[2];
    const float* w_fc  = (const float*)d_in[3];
    const float* b_fc  = (const float*)d_in[4];
    float* out = (float*)d_out;

    const size_t MROWS = (size_t)B_SZ * N_SEQ;  // 8192
    short* xb    = (short*)d_ws;                         // 8192*2048
    short* wqkvt = xb + MROWS * E_DIM;                   // 2304*2048
    short* wfct  = wqkvt + (size_t)QKV_LD * E_DIM;       // 2048*2048
    short* qkvb  = wfct + (size_t)E_DIM * E_DIM;         // 8192*2304
    short* attnb = qkvb + MROWS * QKV_LD;                // 8192*2048
    short* vtg   = xb;   // reuse: xb dead after QKV GEMM

    cast_f32_bf16<<<dim3((int)(MROWS * E_DIM / 1024)), dim3(256), 0, stream>>>(
        x, xb, (int)(MROWS * E_DIM));
    transpose_cast<<<dim3(QKV_LD / 32, E_DIM / 32), dim3(32, 8), 0, stream>>>(
        w_qkv, wqkvt, E_DIM, QKV_LD);
    transpose_cast<<<dim3(E_DIM / 32, E_DIM / 32), dim3(32, 8), 0, stream>>>(
        w_fc, wfct, E_DIM, E_DIM);

    // QKV projection, Q columns (0..2047), scaled by SC2F: 256-grid, one clean round
    gemm256<true, true><<<dim3(E_DIM / 256, (int)(MROWS / 256)), dim3(512), 0, stream>>>(
        xb, wqkvt, b_qkv, qkvb, (int)MROWS, E_DIM, QKV_LD, E_DIM);
    // K/V columns (2048..2303), unscaled: small 128-block 128^2 dispatch
    gemm_bt<true, false><<<dim3(2, (int)(MROWS / 128)), dim3(256), 0, stream>>>(
        xb, wqkvt + (size_t)E_DIM * E_DIM, b_qkv + E_DIM, qkvb + E_DIM,
        (int)MROWS, 2 * D_HEAD, QKV_LD, E_DIM);

    v_transpose<<<dim3(MROWS_T / 32, D_HEAD / 32), dim3(32, 8), 0, stream>>>(qkvb, vtg);

    attn_kernel<<<dim3(8, B_SZ * H_NUM), dim3(256), 0, stream>>>(qkvb, vtg, attnb);

    gemm256<false, false><<<dim3(E_DIM / 256, (int)(MROWS / 256)), dim3(512), 0, stream>>>(
        attnb, wfct, b_fc, out, (int)MROWS, E_DIM, E_DIM, E_DIM);
}

// Round 11
// 419.450 us; speedup vs baseline: 1.5347x; 1.0009x over previous
//
#include <hip/hip_runtime.h>

#define E_DIM 2048
#define H_NUM 16
#define D_HEAD 128
#define B_SZ 4
#define N_SEQ 2048
#define QKV_LD 2304   // E + 2*D
#define MROWS_T (B_SZ * N_SEQ)   // 8192
#define SC2F 0.12751744802582937f  // log2(e)/sqrt(128)

typedef __attribute__((ext_vector_type(8))) __bf16 bfx8;
typedef __attribute__((ext_vector_type(8))) short sx8;
typedef __attribute__((ext_vector_type(4))) short sx4;
typedef __attribute__((ext_vector_type(2))) short sx2;
typedef __attribute__((ext_vector_type(4))) int ix4;
typedef __attribute__((ext_vector_type(4))) float fx4;

__device__ __forceinline__ fx4 mfma_bf16(bfx8 a, bfx8 b, fx4 c) {
    return __builtin_amdgcn_mfma_f32_16x16x32_bf16(a, b, c, 0, 0, 0);
}

// fp32 -> bf16 round-to-nearest-even (finite inputs only)
__device__ __forceinline__ short f2bf(float f) {
    unsigned u = __builtin_bit_cast(unsigned, f);
    u += 0x7FFFu + ((u >> 16) & 1u);
    return (short)(u >> 16);
}

// pack two fp32 -> one dword of two bf16 (lo=a, hi=b)
__device__ __forceinline__ int cvt_pk_bf16(float a, float b) {
    int r;
    asm("v_cvt_pk_bf16_f32 %0, %1, %2" : "=v"(r) : "v"(a), "v"(b));
    return r;
}

__device__ __forceinline__ void gld_lds16(const void* g, void* l) {
    __builtin_amdgcn_global_load_lds((__attribute__((address_space(1))) void*)(void*)g,
                                     (__attribute__((address_space(3))) void*)l, 16, 0, 0);
}

// ---------------- cast fp32 -> bf16 (elementwise, 8/thread) ----------------
__global__ __launch_bounds__(256) void cast_f32_bf16(const float* __restrict__ in,
                                                     short* __restrict__ out, int n) {
    int i = (blockIdx.x * 256 + threadIdx.x) * 8;
    if (i >= n) return;
    float4 v0 = *(const float4*)(in + i);
    float4 v1 = *(const float4*)(in + i + 4);
    sx8 r = {f2bf(v0.x), f2bf(v0.y), f2bf(v0.z), f2bf(v0.w),
             f2bf(v1.x), f2bf(v1.y), f2bf(v1.z), f2bf(v1.w)};
    *(sx8*)(out + i) = r;
}

// ---------------- fused transpose+cast for both weight matrices ----------------
// z=0: w_qkv [E][QKV_LD] -> wqkvt [QKV_LD][E]; z=1: w_fc [E][E] -> wfct [E][E].
// Uniform whole-block early-exit for z=1 bx >= 64 (no barrier reached).
__global__ __launch_bounds__(256) void transpose_cast2(const float* __restrict__ a0,
                                                       short* __restrict__ b0,
                                                       const float* __restrict__ a1,
                                                       short* __restrict__ b1) {
    const float* in; short* out; int C;
    if (blockIdx.z == 0) { in = a0; out = b0; C = QKV_LD; }
    else {
        if (blockIdx.x >= E_DIM / 32) return;
        in = a1; out = b1; C = E_DIM;
    }
    const int R = E_DIM;
    __shared__ float tile[32][33];
    int c0 = blockIdx.x * 32, r0 = blockIdx.y * 32;
    int tx = threadIdx.x;
    for (int i = threadIdx.y; i < 32; i += 8)
        tile[i][tx] = in[(size_t)(r0 + i) * C + c0 + tx];
    __syncthreads();
    for (int i = threadIdx.y; i < 32; i += 8)
        out[(size_t)(c0 + i) * R + r0 + tx] = f2bf(tile[tx][i]);
}

// ---------------- transpose V slice of qkv -> vtg[128][8192] bf16 ----------------
// Key axis stored PERMUTED within each 32-key group: position 2i <- key i,
// position 2i+1 <- key 16+i. With swapped QK^T this is exactly the A-operand k-axis
// order produced by cvt_pk(e_half0, e_half1) per quad: p = 8q+2j+h <-> key 16h+4q+j.
__global__ __launch_bounds__(256) void v_transpose(const short* __restrict__ qkv,
                                                   short* __restrict__ vtg) {
    __shared__ short tile[32][33];
    int r0 = blockIdx.x * 32;
    int d0 = blockIdx.y * 32;
    int tx = threadIdx.x;
    for (int i = threadIdx.y; i < 32; i += 8)
        tile[i][tx] = qkv[(size_t)(r0 + i) * QKV_LD + (E_DIM + D_HEAD) + d0 + tx];
    __syncthreads();
    int kp = ((tx & 15) << 1) | (tx >> 4);   // key-interleave permutation
    for (int i = threadIdx.y; i < 32; i += 8)
        vtg[(size_t)(d0 + i) * MROWS_T + r0 + kp] = tile[tx][i];
}

// ---------------- 128x128 GEMM (m97-structure) — used only for the small K/V slice ----------------
template <bool OUT_BF16, bool SCALE_Q>
__global__ __launch_bounds__(256) void gemm_bt(const short* __restrict__ A,
                                               const short* __restrict__ Bt,
                                               const float* __restrict__ bias,
                                               void* __restrict__ Cp,
                                               int M, int N, int ldc, int K) {
    __shared__ __align__(16) short As[128 * 32];
    __shared__ __align__(16) short Bs[128 * 32];
    const int tid = threadIdx.x, wave = tid >> 6, lane = tid & 63;
    const int quad = lane >> 4, l16 = lane & 15;

    const int gx = gridDim.x;
    int wg = blockIdx.y * gx + blockIdx.x;
    {
        const int nwg = gx * gridDim.y;
        const int qd = nwg >> 3, rm = nwg & 7;
        const int xcd = wg & 7, loc = wg >> 3;
        wg = (xcd < rm ? xcd * (qd + 1) : rm * (qd + 1) + (xcd - rm) * qd) + loc;
    }
    const int m0 = (wg / gx) * 128, n0 = (wg % gx) * 128;

    const int wm = (wave >> 1) * 64, wn = (wave & 1) * 64;
    const int srow = lane >> 2, scol = (lane & 3) * 8;

    fx4 acc[4][4];
#pragma unroll
    for (int mt = 0; mt < 4; ++mt)
#pragma unroll
        for (int nt = 0; nt < 4; ++nt) acc[mt][nt] = (fx4){0.f, 0.f, 0.f, 0.f};

    const short* Ag = A + (size_t)m0 * K;
    const short* Bg = Bt + (size_t)n0 * K;

    for (int k0 = 0; k0 < K; k0 += 32) {
#pragma unroll
        for (int i = 0; i < 2; ++i) {
            int chunk = wave * 2 + i;
            int row = chunk * 16 + srow;
            gld_lds16(Ag + (size_t)row * K + k0 + scol, &As[chunk * 512]);
            gld_lds16(Bg + (size_t)row * K + k0 + scol, &Bs[chunk * 512]);
        }
        __syncthreads();
        bfx8 af[4], bfr[4];
#pragma unroll
        for (int t = 0; t < 4; ++t) {
            af[t]  = *(const bfx8*)&As[(wm + t * 16 + l16) * 32 + quad * 8];
            bfr[t] = *(const bfx8*)&Bs[(wn + t * 16 + l16) * 32 + quad * 8];
        }
#pragma unroll
        for (int mt = 0; mt < 4; ++mt)
#pragma unroll
            for (int nt = 0; nt < 4; ++nt)
                acc[mt][nt] = mfma_bf16(af[mt], bfr[nt], acc[mt][nt]);
        __syncthreads();
    }

    const float scl = (SCALE_Q && n0 < E_DIM) ? SC2F : 1.0f;
    float bv[4];
#pragma unroll
    for (int nt = 0; nt < 4; ++nt) bv[nt] = bias[n0 + wn + nt * 16 + l16];

#pragma unroll
    for (int mt = 0; mt < 4; ++mt)
#pragma unroll
        for (int nt = 0; nt < 4; ++nt)
#pragma unroll
            for (int j = 0; j < 4; ++j) {
                int row = m0 + wm + mt * 16 + quad * 4 + j;
                int col = n0 + wn + nt * 16 + l16;
                float v = (acc[mt][nt][j] + bv[nt]) * scl;
                if (OUT_BF16)
                    ((short*)Cp)[(size_t)row * ldc + col] = f2bf(v);
                else
                    ((float*)Cp)[(size_t)row * ldc + col] = v;
            }
}

// ---------------- 256x256 8-phase GEMM (T2+T3+T4+T5), BK=64, 512 threads ----------------
// ROUND-2 SCHEDULE (harness-verified) + T1/m204 bijective XCD block swizzle.
template <bool OUT_BF16, bool SCALE_ALL>
__global__ __launch_bounds__(512) void gemm256(const short* __restrict__ A,
                                               const short* __restrict__ Bt,
                                               const float* __restrict__ bias,
                                               void* __restrict__ Cp,
                                               int M, int N, int ldc, int K) {
    __shared__ __align__(16) short lds[2][2][2][8192];   // [buf][kk][A=0/B=1][256*32]
    const int tid = threadIdx.x, wave = tid >> 6, lane = tid & 63;
    const int quad = lane >> 4, l16 = lane & 15;
    const int wmi = wave >> 2, wni = wave & 3;   // 2M x 4N wave grid

    const int gx = gridDim.x;
    int wg = blockIdx.y * gx + blockIdx.x;
    {
        const int nwg = gx * gridDim.y;
        const int qd = nwg >> 3, rm = nwg & 7;
        const int xcd = wg & 7, loc = wg >> 3;
        wg = (xcd < rm ? xcd * (qd + 1) : rm * (qd + 1) + (xcd - rm) * qd) + loc;
    }
    const int m0 = (wg / gx) * 256, n0 = (wg % gx) * 256;

    const size_t rstep = (size_t)128 * K;
    const int srow = wave * 16 + (lane >> 2);
    const int sslot = (lane & 3) ^ ((lane >> 3) & 3);
    const short* Asrc = A + ((size_t)(m0 + srow)) * K + sslot * 8;
    const short* Bsrc = Bt + ((size_t)(n0 + srow)) * K + sslot * 8;

    auto stage = [&](const short* srcb, short* dstb, int kcol0) {
        gld_lds16(srcb + kcol0, dstb + wave * 512);
        gld_lds16(srcb + kcol0 + rstep, dstb + 4096 + wave * 512);
    };

    // fragment read offsets (swizzled): 16B-slot ^= (row>>1)&3
    const int swl = (l16 >> 1) & 3;
    const int aoff = (wmi * 128 + l16) * 32 + (quad ^ swl) * 8;
    const int boff = (wni * 64 + l16) * 32 + (quad ^ swl) * 8;

    fx4 acc[8][4];
#pragma unroll
    for (int m = 0; m < 8; ++m)
#pragma unroll
        for (int n = 0; n < 4; ++n) acc[m][n] = (fx4){0.f, 0.f, 0.f, 0.f};

    const int nt = K >> 6;

    // prologue: tile0 all 4 halves + tile1 k0; allow newest 2 halves outstanding
    stage(Asrc, &lds[0][0][0][0], 0);
    stage(Bsrc, &lds[0][0][1][0], 0);
    stage(Asrc, &lds[0][1][0][0], 32);
    stage(Bsrc, &lds[0][1][1][0], 32);
    stage(Asrc, &lds[1][0][0][0], 64);
    stage(Bsrc, &lds[1][0][1][0], 64);
    asm volatile("s_waitcnt vmcnt(4)");
    __builtin_amdgcn_s_barrier();
    __builtin_amdgcn_sched_barrier(0);

#pragma unroll 1
    for (int t = 0; t < nt; ++t) {
        const int cur = t & 1, nxt = cur ^ 1;
        const short* Ah0 = &lds[cur][0][0][0];
        const short* Bh0 = &lds[cur][0][1][0];
        const short* Ah1 = &lds[cur][1][0][0];
        const short* Bh1 = &lds[cur][1][1][0];
        const int kc = t * 64;
        bfx8 af[4], bf0[4], bf1[4];

        // ---- phase 0: kk=0, m 0-3 ----
#pragma unroll
        for (int n = 0; n < 4; ++n) bf0[n] = *(const bfx8*)&Bh0[boff + n * 512];
#pragma unroll
        for (int m = 0; m < 4; ++m) af[m] = *(const bfx8*)&Ah0[aoff + m * 512];
        if (t + 1 < nt) stage(Asrc, &lds[nxt][1][0][0], kc + 96);
        __builtin_amdgcn_s_barrier();
        __builtin_amdgcn_sched_barrier(0);
        __builtin_amdgcn_s_setprio(1);
#pragma unroll
        for (int m = 0; m < 4; ++m)
#pragma unroll
            for (int n = 0; n < 4; ++n) acc[m][n] = mfma_bf16(af[m], bf0[n], acc[m][n]);
        __builtin_amdgcn_s_setprio(0);
        __builtin_amdgcn_s_barrier();
        __builtin_amdgcn_sched_barrier(0);

        // ---- phase 1: kk=0, m 4-7 ----
#pragma unroll
        for (int m = 0; m < 4; ++m) af[m] = *(const bfx8*)&Ah0[aoff + (m + 4) * 512];
        if (t + 1 < nt) stage(Bsrc, &lds[nxt][1][1][0], kc + 96);
        __builtin_amdgcn_s_barrier();
        __builtin_amdgcn_sched_barrier(0);
        __builtin_amdgcn_s_setprio(1);
#pragma unroll
        for (int m = 0; m < 4; ++m)
#pragma unroll
            for (int n = 0; n < 4; ++n) acc[m + 4][n] = mfma_bf16(af[m], bf0[n], acc[m + 4][n]);
        __builtin_amdgcn_s_setprio(0);
        __builtin_amdgcn_s_barrier();
        __builtin_amdgcn_sched_barrier(0);

        // ---- phase 2: kk=1, m 0-3 ----
#pragma unroll
        for (int n = 0; n < 4; ++n) bf1[n] = *(const bfx8*)&Bh1[boff + n * 512];
#pragma unroll
        for (int m = 0; m < 4; ++m) af[m] = *(const bfx8*)&Ah1[aoff + m * 512];
        if (t + 2 < nt) stage(Asrc, &lds[cur][0][0][0], kc + 128);
        __builtin_amdgcn_s_barrier();
        __builtin_amdgcn_sched_barrier(0);
        __builtin_amdgcn_s_setprio(1);
#pragma unroll
        for (int m = 0; m < 4; ++m)
#pragma unroll
            for (int n = 0; n < 4; ++n) acc[m][n] = mfma_bf16(af[m], bf1[n], acc[m][n]);
        __builtin_amdgcn_s_setprio(0);
        __builtin_amdgcn_s_barrier();
        __builtin_amdgcn_sched_barrier(0);

        // ---- phase 3: kk=1, m 4-7 ----
#pragma unroll
        for (int m = 0; m < 4; ++m) af[m] = *(const bfx8*)&Ah1[aoff + (m + 4) * 512];
        if (t + 2 < nt) stage(Bsrc, &lds[cur][0][1][0], kc + 128);
        __builtin_amdgcn_s_barrier();
        __builtin_amdgcn_sched_barrier(0);
        __builtin_amdgcn_s_setprio(1);
#pragma unroll
        for (int m = 0; m < 4; ++m)
#pragma unroll
            for (int n = 0; n < 4; ++n) acc[m + 4][n] = mfma_bf16(af[m], bf1[n], acc[m + 4][n]);
        __builtin_amdgcn_s_setprio(0);
        if (t < nt - 2) asm volatile("s_waitcnt vmcnt(4)");
        else            asm volatile("s_waitcnt vmcnt(0)");
        __builtin_amdgcn_s_barrier();
        __builtin_amdgcn_sched_barrier(0);
    }

    const float scl = SCALE_ALL ? SC2F : 1.0f;
    float bvn[4];
#pragma unroll
    for (int n = 0; n < 4; ++n) bvn[n] = bias[n0 + wni * 64 + n * 16 + l16];

#pragma unroll
    for (int m = 0; m < 8; ++m)
#pragma unroll
        for (int n = 0; n < 4; ++n)
#pragma unroll
            for (int j = 0; j < 4; ++j) {
                int row = m0 + wmi * 128 + m * 16 + quad * 4 + j;
                int col = n0 + wni * 64 + n * 16 + l16;
                float v = (acc[m][n][j] + bvn[n]) * scl;
                if (OUT_BF16)
                    ((short*)Cp)[(size_t)row * ldc + col] = f2bf(v);
                else
                    ((float*)Cp)[(size_t)row * ldc + col] = v;
            }
}

// ---------------- Flash attention (multi-query, causal) ----------------
// ROUND-9 VERIFIED SOURCE (99.4us, conflicts=0). Paired structure (grid 8 x 64, halves
// (bx, 15-bx) -> uniform 68 tiles; co-scheduled same-(b,h) blocks = the L2 strategy).
// SWAPPED QK^T (T12): s = mfma(K, Q) -> lane l16 holds P[q=l16][keys quad*4+j] for
// both 16-key halves. cvt_pk(e_h0[j], e_h1[j]) builds the PV A-fragment DIRECTLY in
// registers under the k-axis permutation p=8q+2j+h <-> key 16h+4q+j (= vtg's stored
// key order) -> no P-tile LDS round-trip. K/V LDS: involution slot-swizzle
// sigma(s)=s^((s>>3)&7) on 16B slots; V fragments hoisted before the softmax.
__global__ __launch_bounds__(256, 2) void attn_kernel(const short* __restrict__ qkv,
                                                      const short* __restrict__ vtg,
                                                      short* __restrict__ outp) {
    __shared__ __align__(16) short Ks[2][4096];
    __shared__ __align__(16) short Vt[2][4096];
    const int b = blockIdx.y >> 4, h = blockIdx.y & 15;
    const int tid = threadIdx.x, wave = tid >> 6, lane = tid & 63;
    const int quad = lane >> 4, l16 = lane & 15;
    const size_t baseRow = (size_t)b * N_SEQ;

    // staging: lane l fetches logical slot sigma(l) = l ^ ((l>>3)&7)
    const int sl = lane ^ ((lane >> 3) & 7);
    const int srow = sl >> 2, sq = sl & 3;
    // read: logical slot (l16*4+quad) lives at physical slot ^ ((l16>>1)&7)
    const int rslot = ((l16 * 4 + quad) ^ ((l16 >> 1) & 7)) * 8;

    auto stage = [&](int k0, int bufi) {
#pragma unroll
        for (int i = 0; i < 2; ++i) {
            const int c = wave * 2 + i;
            gld_lds16(qkv + (baseRow + k0 + (c & 1) * 16 + srow) * QKV_LD + E_DIM +
                          (c >> 1) * 32 + sq * 8,
                      &Ks[bufi][c * 512]);
            gld_lds16(vtg + (size_t)(c * 16 + srow) * MROWS_T + baseRow + k0 + sq * 8,
                      &Vt[bufi][c * 512]);
        }
    };

#pragma unroll 1
    for (int half = 0; half < 2; ++half) {
        const int chunk = half ? (15 - blockIdx.x) : blockIdx.x;
        const int q0 = chunk * 128;
        const int wrow = q0 + wave * 32;

        bfx8 aq0[4], aq1[4];
        {
            const short* qb0 = qkv + (baseRow + wrow + l16) * QKV_LD + h * D_HEAD + quad * 8;
            const short* qb1 = qb0 + 16 * QKV_LD;
#pragma unroll
            for (int c = 0; c < 4; ++c) {
                aq0[c] = *(const bfx8*)(qb0 + c * 32);
                aq1[c] = *(const bfx8*)(qb1 + c * 32);
            }
        }

        fx4 accO0[8], accO1[8];
        float l0 = 0.f, l1 = 0.f;
#pragma unroll
        for (int dt = 0; dt < 8; ++dt) {
            accO0[dt] = (fx4){0.f, 0.f, 0.f, 0.f};
            accO1[dt] = (fx4){0.f, 0.f, 0.f, 0.f};
        }

        const int nbulk = 4 * chunk;
        const int nkt = nbulk + 4;

        __syncthreads();   // all waves done reading LDS from previous half
        stage(0, 0);

#pragma unroll 1
        for (int kt = 0; kt < nkt; ++kt) {
            __syncthreads();   // buf[kt&1] ready (vmcnt drain hidden by previous compute)
            if (kt + 1 < nkt) stage((kt + 1) << 5, (kt + 1) & 1);
            const short* ks = Ks[kt & 1];
            const short* vs = Vt[kt & 1];
            const int k0 = kt << 5;

            // SWAPPED S^T = K Q^T: lane l16 holds P[q=l16][key = k0 + 16h + quad*4+j]
            fx4 s00 = {0.f, 0.f, 0.f, 0.f}, s01 = {0.f, 0.f, 0.f, 0.f};
            fx4 s10 = {0.f, 0.f, 0.f, 0.f}, s11 = {0.f, 0.f, 0.f, 0.f};
            __builtin_amdgcn_s_setprio(1);
#pragma unroll
            for (int dc = 0; dc < 4; ++dc) {
                bfx8 kf0 = *(const bfx8*)&ks[(dc * 2 + 0) * 512 + rslot];
                bfx8 kf1 = *(const bfx8*)&ks[(dc * 2 + 1) * 512 + rslot];
                s00 = mfma_bf16(kf0, aq0[dc], s00);
                s01 = mfma_bf16(kf1, aq0[dc], s01);
                s10 = mfma_bf16(kf0, aq1[dc], s10);
                s11 = mfma_bf16(kf1, aq1[dc], s11);
            }
            __builtin_amdgcn_s_setprio(0);

            // hoist V fragments: DS latency overlaps the softmax VALU below
            bfx8 bvr[8];
#pragma unroll
            for (int dt = 0; dt < 8; ++dt)
                bvr[dt] = *(const bfx8*)&vs[dt * 512 + rslot];

            const bool diag = kt >= nbulk;
            int pk0[4], pk1[4];
#pragma unroll
            for (int j = 0; j < 4; ++j) {
                float e0 = __builtin_amdgcn_exp2f(s00[j]);
                float e1 = __builtin_amdgcn_exp2f(s01[j]);
                if (diag) {
                    const int key = k0 + quad * 4 + j;
                    const int qr = wrow + l16;
                    e0 = (key <= qr) ? e0 : 0.f;
                    e1 = (key + 16 <= qr) ? e1 : 0.f;
                }
                l0 += e0 + e1;
                pk0[j] = cvt_pk_bf16(e0, e1);
            }
#pragma unroll
            for (int j = 0; j < 4; ++j) {
                float e0 = __builtin_amdgcn_exp2f(s10[j]);
                float e1 = __builtin_amdgcn_exp2f(s11[j]);
                if (diag) {
                    const int key = k0 + quad * 4 + j;
                    const int qr = wrow + 16 + l16;
                    e0 = (key <= qr) ? e0 : 0.f;
                    e1 = (key + 16 <= qr) ? e1 : 0.f;
                }
                l1 += e0 + e1;
                pk1[j] = cvt_pk_bf16(e0, e1);
            }

            bfx8 ap0 = __builtin_bit_cast(bfx8, (ix4){pk0[0], pk0[1], pk0[2], pk0[3]});
            bfx8 ap1 = __builtin_bit_cast(bfx8, (ix4){pk1[0], pk1[1], pk1[2], pk1[3]});
            __builtin_amdgcn_s_setprio(1);
#pragma unroll
            for (int dt = 0; dt < 8; ++dt) {
                accO0[dt] = mfma_bf16(ap0, bvr[dt], accO0[dt]);
                accO1[dt] = mfma_bf16(ap1, bvr[dt], accO1[dt]);
            }
            __builtin_amdgcn_s_setprio(0);
        }

        // l currently per-lane partial over this quad's keys; reduce across quads
        // (lane bits 4,5) -> every lane holds L[q = wrow (+16) + l16]
        l0 += __shfl_xor(l0, 16); l0 += __shfl_xor(l0, 32);
        l1 += __shfl_xor(l1, 16); l1 += __shfl_xor(l1, 32);

#pragma unroll
        for (int j = 0; j < 4; ++j) {
            // output row q = wrow + quad*4 + j; its L lives at lane l16 = quad*4+j
            float rl0 = 1.0f / __shfl(l0, quad * 4 + j);
            float rl1 = 1.0f / __shfl(l1, quad * 4 + j);
            size_t ob0 = (baseRow + wrow + quad * 4 + j) * (size_t)E_DIM + h * D_HEAD + l16;
            size_t ob1 = ob0 + (size_t)16 * E_DIM;
#pragma unroll
            for (int dt = 0; dt < 8; ++dt) {
                outp[ob0 + dt * 16] = f2bf(accO0[dt][j] * rl0);
                outp[ob1 + dt * 16] = f2bf(accO1[dt][j] * rl1);
            }
        }
    }
}

extern "C" void kernel_launch(void* const* d_in, const int* in_sizes, int n_in,
                              void* d_out, int out_size, void* d_ws, size_t ws_size,
                              hipStream_t stream) {
    const float* x     = (const float*)d_in[0];
    const float* w_qkv = (const float*)d_in[1];
    const float* b_qkv = (const float*)d_in[2];
    const float* w_fc  = (const float*)d_in[3];
    const float* b_fc  = (const float*)d_in[4];
    float* out = (float*)d_out;

    const size_t MROWS = (size_t)B_SZ * N_SEQ;  // 8192
    short* xb    = (short*)d_ws;                         // 8192*2048
    short* wqkvt = xb + MROWS * E_DIM;                   // 2304*2048
    short* wfct  = wqkvt + (size_t)QKV_LD * E_DIM;       // 2048*2048
    short* qkvb  = wfct + (size_t)E_DIM * E_DIM;         // 8192*2304
    short* attnb = qkvb + MROWS * QKV_LD;                // 8192*2048
    short* vtg   = xb;   // reuse: xb dead after QKV GEMM

    cast_f32_bf16<<<dim3((int)(MROWS * E_DIM / 2048)), dim3(256), 0, stream>>>(
        x, xb, (int)(MROWS * E_DIM));
    transpose_cast2<<<dim3(QKV_LD / 32, E_DIM / 32, 2), dim3(32, 8), 0, stream>>>(
        w_qkv, wqkvt, w_fc, wfct);

    // QKV projection, Q columns (0..2047), scaled by SC2F: 256-grid, one clean round
    gemm256<true, true><<<dim3(E_DIM / 256, (int)(MROWS / 256)), dim3(512), 0, stream>>>(
        xb, wqkvt, b_qkv, qkvb, (int)MROWS, E_DIM, QKV_LD, E_DIM);
    // K/V columns (2048..2303), unscaled: small 128-block 128^2 dispatch
    gemm_bt<true, false><<<dim3(2, (int)(MROWS / 128)), dim3(256), 0, stream>>>(
        xb, wqkvt + (size_t)E_DIM * E_DIM, b_qkv + E_DIM, qkvb + E_DIM,
        (int)MROWS, 2 * D_HEAD, QKV_LD, E_DIM);

    v_transpose<<<dim3(MROWS_T / 32, D_HEAD / 32), dim3(32, 8), 0, stream>>>(qkvb, vtg);

    attn_kernel<<<dim3(8, B_SZ * H_NUM), dim3(256), 0, stream>>>(qkvb, vtg, attnb);

    gemm256<false, false><<<dim3(E_DIM / 256, (int)(MROWS / 256)), dim3(512), 0, stream>>>(
        attnb, wfct, b_fc, out, (int)MROWS, E_DIM, E_DIM, E_DIM);
}

// Round 12
// 413.948 us; speedup vs baseline: 1.5551x; 1.0133x over previous
//
#include <hip/hip_runtime.h>

#define E_DIM 2048
#define H_NUM 16
#define D_HEAD 128
#define B_SZ 4
#define N_SEQ 2048
#define QKV_LD 2304   // E + 2*D
#define MROWS_T (B_SZ * N_SEQ)   // 8192
#define SC2F 0.12751744802582937f  // log2(e)/sqrt(128)

typedef __attribute__((ext_vector_type(8))) __bf16 bfx8;
typedef __attribute__((ext_vector_type(8))) short sx8;
typedef __attribute__((ext_vector_type(4))) short sx4;
typedef __attribute__((ext_vector_type(2))) short sx2;
typedef __attribute__((ext_vector_type(4))) int ix4;
typedef __attribute__((ext_vector_type(4))) float fx4;

__device__ __forceinline__ fx4 mfma_bf16(bfx8 a, bfx8 b, fx4 c) {
    return __builtin_amdgcn_mfma_f32_16x16x32_bf16(a, b, c, 0, 0, 0);
}

// fp32 -> bf16 round-to-nearest-even (finite inputs only)
__device__ __forceinline__ short f2bf(float f) {
    unsigned u = __builtin_bit_cast(unsigned, f);
    u += 0x7FFFu + ((u >> 16) & 1u);
    return (short)(u >> 16);
}

// pack two fp32 -> one dword of two bf16 (lo=a, hi=b)
__device__ __forceinline__ int cvt_pk_bf16(float a, float b) {
    int r;
    asm("v_cvt_pk_bf16_f32 %0, %1, %2" : "=v"(r) : "v"(a), "v"(b));
    return r;
}

__device__ __forceinline__ void gld_lds16(const void* g, void* l) {
    __builtin_amdgcn_global_load_lds((__attribute__((address_space(1))) void*)(void*)g,
                                     (__attribute__((address_space(3))) void*)l, 16, 0, 0);
}

// ---------------- cast fp32 -> bf16 (elementwise, 8/thread) ----------------
__global__ __launch_bounds__(256) void cast_f32_bf16(const float* __restrict__ in,
                                                     short* __restrict__ out, int n) {
    int i = (blockIdx.x * 256 + threadIdx.x) * 8;
    if (i >= n) return;
    float4 v0 = *(const float4*)(in + i);
    float4 v1 = *(const float4*)(in + i + 4);
    sx8 r = {f2bf(v0.x), f2bf(v0.y), f2bf(v0.z), f2bf(v0.w),
             f2bf(v1.x), f2bf(v1.y), f2bf(v1.z), f2bf(v1.w)};
    *(sx8*)(out + i) = r;
}

// ---------------- fused transpose+cast for both weight matrices ----------------
// z=0: w_qkv [E][QKV_LD] -> wqkvt [QKV_LD][E]; z=1: w_fc [E][E] -> wfct [E][E].
// Uniform whole-block early-exit for z=1 bx >= 64 (no barrier reached).
__global__ __launch_bounds__(256) void transpose_cast2(const float* __restrict__ a0,
                                                       short* __restrict__ b0,
                                                       const float* __restrict__ a1,
                                                       short* __restrict__ b1) {
    const float* in; short* out; int C;
    if (blockIdx.z == 0) { in = a0; out = b0; C = QKV_LD; }
    else {
        if (blockIdx.x >= E_DIM / 32) return;
        in = a1; out = b1; C = E_DIM;
    }
    const int R = E_DIM;
    __shared__ float tile[32][33];
    int c0 = blockIdx.x * 32, r0 = blockIdx.y * 32;
    int tx = threadIdx.x;
    for (int i = threadIdx.y; i < 32; i += 8)
        tile[i][tx] = in[(size_t)(r0 + i) * C + c0 + tx];
    __syncthreads();
    for (int i = threadIdx.y; i < 32; i += 8)
        out[(size_t)(c0 + i) * R + r0 + tx] = f2bf(tile[tx][i]);
}

// ---------------- transpose V slice of qkv -> vtg[128][8192] bf16 ----------------
// Key axis stored PERMUTED within each 32-key group: position 2i <- key i,
// position 2i+1 <- key 16+i. With swapped QK^T this is exactly the A-operand k-axis
// order produced by cvt_pk(e_half0, e_half1) per quad: p = 8q+2j+h <-> key 16h+4q+j.
__global__ __launch_bounds__(256) void v_transpose(const short* __restrict__ qkv,
                                                   short* __restrict__ vtg) {
    __shared__ short tile[32][33];
    int r0 = blockIdx.x * 32;
    int d0 = blockIdx.y * 32;
    int tx = threadIdx.x;
    for (int i = threadIdx.y; i < 32; i += 8)
        tile[i][tx] = qkv[(size_t)(r0 + i) * QKV_LD + (E_DIM + D_HEAD) + d0 + tx];
    __syncthreads();
    int kp = ((tx & 15) << 1) | (tx >> 4);   // key-interleave permutation
    for (int i = threadIdx.y; i < 32; i += 8)
        vtg[(size_t)(d0 + i) * MROWS_T + r0 + kp] = tile[tx][i];
}

// ---------------- 128x128 GEMM (m97-structure) — used only for the small K/V slice ----------------
template <bool OUT_BF16, bool SCALE_Q>
__global__ __launch_bounds__(256) void gemm_bt(const short* __restrict__ A,
                                               const short* __restrict__ Bt,
                                               const float* __restrict__ bias,
                                               void* __restrict__ Cp,
                                               int M, int N, int ldc, int K) {
    __shared__ __align__(16) short As[128 * 32];
    __shared__ __align__(16) short Bs[128 * 32];
    const int tid = threadIdx.x, wave = tid >> 6, lane = tid & 63;
    const int quad = lane >> 4, l16 = lane & 15;

    const int gx = gridDim.x;
    int wg = blockIdx.y * gx + blockIdx.x;
    {
        const int nwg = gx * gridDim.y;
        const int qd = nwg >> 3, rm = nwg & 7;
        const int xcd = wg & 7, loc = wg >> 3;
        wg = (xcd < rm ? xcd * (qd + 1) : rm * (qd + 1) + (xcd - rm) * qd) + loc;
    }
    const int m0 = (wg / gx) * 128, n0 = (wg % gx) * 128;

    const int wm = (wave >> 1) * 64, wn = (wave & 1) * 64;
    const int srow = lane >> 2, scol = (lane & 3) * 8;

    fx4 acc[4][4];
#pragma unroll
    for (int mt = 0; mt < 4; ++mt)
#pragma unroll
        for (int nt = 0; nt < 4; ++nt) acc[mt][nt] = (fx4){0.f, 0.f, 0.f, 0.f};

    const short* Ag = A + (size_t)m0 * K;
    const short* Bg = Bt + (size_t)n0 * K;

    for (int k0 = 0; k0 < K; k0 += 32) {
#pragma unroll
        for (int i = 0; i < 2; ++i) {
            int chunk = wave * 2 + i;
            int row = chunk * 16 + srow;
            gld_lds16(Ag + (size_t)row * K + k0 + scol, &As[chunk * 512]);
            gld_lds16(Bg + (size_t)row * K + k0 + scol, &Bs[chunk * 512]);
        }
        __syncthreads();
        bfx8 af[4], bfr[4];
#pragma unroll
        for (int t = 0; t < 4; ++t) {
            af[t]  = *(const bfx8*)&As[(wm + t * 16 + l16) * 32 + quad * 8];
            bfr[t] = *(const bfx8*)&Bs[(wn + t * 16 + l16) * 32 + quad * 8];
        }
#pragma unroll
        for (int mt = 0; mt < 4; ++mt)
#pragma unroll
            for (int nt = 0; nt < 4; ++nt)
                acc[mt][nt] = mfma_bf16(af[mt], bfr[nt], acc[mt][nt]);
        __syncthreads();
    }

    const float scl = (SCALE_Q && n0 < E_DIM) ? SC2F : 1.0f;
    float bv[4];
#pragma unroll
    for (int nt = 0; nt < 4; ++nt) bv[nt] = bias[n0 + wn + nt * 16 + l16];

#pragma unroll
    for (int mt = 0; mt < 4; ++mt)
#pragma unroll
        for (int nt = 0; nt < 4; ++nt)
#pragma unroll
            for (int j = 0; j < 4; ++j) {
                int row = m0 + wm + mt * 16 + quad * 4 + j;
                int col = n0 + wn + nt * 16 + l16;
                float v = (acc[mt][nt][j] + bv[nt]) * scl;
                if (OUT_BF16)
                    ((short*)Cp)[(size_t)row * ldc + col] = f2bf(v);
                else
                    ((float*)Cp)[(size_t)row * ldc + col] = v;
            }
}

// ---------------- 256x256 GEMM, BK=64, 512 threads, 2 merged phases/tile ----------------
// Same stage targets and vmcnt ledger as the harness-verified round-2 schedule; the two
// m-half phases per k-slice are MERGED (32 MFMA per phase) -> 4 barriers/tile instead
// of 8. Ledger (2 gld_lds per stage call):
//   phase A (kk=0): reads Bh0/Ah0 (12 ds_reads); stages (t+1).A.k1 + (t+1).B.k1
//   phase B (kk=1): reads Bh1/Ah1; stages (t+2).A.k0 + (t+2).B.k0
//   vmcnt(4) at tile end retires everything through (t+1)'s four buffers; WAW: every
//   staged slot's previous readers lgkm-retired >=1 barrier before the stage issue.
// + T1/m204 bijective XCD block swizzle.
template <bool OUT_BF16, bool SCALE_ALL>
__global__ __launch_bounds__(512) void gemm256(const short* __restrict__ A,
                                               const short* __restrict__ Bt,
                                               const float* __restrict__ bias,
                                               void* __restrict__ Cp,
                                               int M, int N, int ldc, int K) {
    __shared__ __align__(16) short lds[2][2][2][8192];   // [buf][kk][A=0/B=1][256*32]
    const int tid = threadIdx.x, wave = tid >> 6, lane = tid & 63;
    const int quad = lane >> 4, l16 = lane & 15;
    const int wmi = wave >> 2, wni = wave & 3;   // 2M x 4N wave grid

    const int gx = gridDim.x;
    int wg = blockIdx.y * gx + blockIdx.x;
    {
        const int nwg = gx * gridDim.y;
        const int qd = nwg >> 3, rm = nwg & 7;
        const int xcd = wg & 7, loc = wg >> 3;
        wg = (xcd < rm ? xcd * (qd + 1) : rm * (qd + 1) + (xcd - rm) * qd) + loc;
    }
    const int m0 = (wg / gx) * 256, n0 = (wg % gx) * 256;

    const size_t rstep = (size_t)128 * K;
    const int srow = wave * 16 + (lane >> 2);
    const int sslot = (lane & 3) ^ ((lane >> 3) & 3);
    const short* Asrc = A + ((size_t)(m0 + srow)) * K + sslot * 8;
    const short* Bsrc = Bt + ((size_t)(n0 + srow)) * K + sslot * 8;

    auto stage = [&](const short* srcb, short* dstb, int kcol0) {
        gld_lds16(srcb + kcol0, dstb + wave * 512);
        gld_lds16(srcb + kcol0 + rstep, dstb + 4096 + wave * 512);
    };

    // fragment read offsets (swizzled): 16B-slot ^= (row>>1)&3
    const int swl = (l16 >> 1) & 3;
    const int aoff = (wmi * 128 + l16) * 32 + (quad ^ swl) * 8;
    const int boff = (wni * 64 + l16) * 32 + (quad ^ swl) * 8;

    fx4 acc[8][4];
#pragma unroll
    for (int m = 0; m < 8; ++m)
#pragma unroll
        for (int n = 0; n < 4; ++n) acc[m][n] = (fx4){0.f, 0.f, 0.f, 0.f};

    const int nt = K >> 6;

    // prologue: tile0 all 4 halves + tile1 k0; allow newest 2 halves outstanding
    stage(Asrc, &lds[0][0][0][0], 0);
    stage(Bsrc, &lds[0][0][1][0], 0);
    stage(Asrc, &lds[0][1][0][0], 32);
    stage(Bsrc, &lds[0][1][1][0], 32);
    stage(Asrc, &lds[1][0][0][0], 64);
    stage(Bsrc, &lds[1][0][1][0], 64);
    asm volatile("s_waitcnt vmcnt(4)");
    __builtin_amdgcn_s_barrier();
    __builtin_amdgcn_sched_barrier(0);

#pragma unroll 1
    for (int t = 0; t < nt; ++t) {
        const int cur = t & 1, nxt = cur ^ 1;
        const short* Ah0 = &lds[cur][0][0][0];
        const short* Bh0 = &lds[cur][0][1][0];
        const short* Ah1 = &lds[cur][1][0][0];
        const short* Bh1 = &lds[cur][1][1][0];
        const int kc = t * 64;
        bfx8 af[8], bfr[4];

        // ---- phase A: kk=0, all m ----
#pragma unroll
        for (int n = 0; n < 4; ++n) bfr[n] = *(const bfx8*)&Bh0[boff + n * 512];
#pragma unroll
        for (int m = 0; m < 8; ++m) af[m] = *(const bfx8*)&Ah0[aoff + m * 512];
        if (t + 1 < nt) {
            stage(Asrc, &lds[nxt][1][0][0], kc + 96);
            stage(Bsrc, &lds[nxt][1][1][0], kc + 96);
        }
        __builtin_amdgcn_s_barrier();
        __builtin_amdgcn_sched_barrier(0);
        __builtin_amdgcn_s_setprio(1);
#pragma unroll
        for (int m = 0; m < 8; ++m)
#pragma unroll
            for (int n = 0; n < 4; ++n) acc[m][n] = mfma_bf16(af[m], bfr[n], acc[m][n]);
        __builtin_amdgcn_s_setprio(0);
        __builtin_amdgcn_s_barrier();
        __builtin_amdgcn_sched_barrier(0);

        // ---- phase B: kk=1, all m ----
#pragma unroll
        for (int n = 0; n < 4; ++n) bfr[n] = *(const bfx8*)&Bh1[boff + n * 512];
#pragma unroll
        for (int m = 0; m < 8; ++m) af[m] = *(const bfx8*)&Ah1[aoff + m * 512];
        if (t + 2 < nt) {
            stage(Asrc, &lds[cur][0][0][0], kc + 128);
            stage(Bsrc, &lds[cur][0][1][0], kc + 128);
        }
        __builtin_amdgcn_s_barrier();
        __builtin_amdgcn_sched_barrier(0);
        __builtin_amdgcn_s_setprio(1);
#pragma unroll
        for (int m = 0; m < 8; ++m)
#pragma unroll
            for (int n = 0; n < 4; ++n) acc[m][n] = mfma_bf16(af[m], bfr[n], acc[m][n]);
        __builtin_amdgcn_s_setprio(0);
        if (t < nt - 2) asm volatile("s_waitcnt vmcnt(4)");
        else            asm volatile("s_waitcnt vmcnt(0)");
        __builtin_amdgcn_s_barrier();
        __builtin_amdgcn_sched_barrier(0);
    }

    const float scl = SCALE_ALL ? SC2F : 1.0f;
    float bvn[4];
#pragma unroll
    for (int n = 0; n < 4; ++n) bvn[n] = bias[n0 + wni * 64 + n * 16 + l16];

#pragma unroll
    for (int m = 0; m < 8; ++m)
#pragma unroll
        for (int n = 0; n < 4; ++n)
#pragma unroll
            for (int j = 0; j < 4; ++j) {
                int row = m0 + wmi * 128 + m * 16 + quad * 4 + j;
                int col = n0 + wni * 64 + n * 16 + l16;
                float v = (acc[m][n][j] + bvn[n]) * scl;
                if (OUT_BF16)
                    ((short*)Cp)[(size_t)row * ldc + col] = f2bf(v);
                else
                    ((float*)Cp)[(size_t)row * ldc + col] = v;
            }
}

// ---------------- Flash attention (multi-query, causal) ----------------
// ROUND-9/11 VERIFIED SOURCE (99.4us, conflicts=0). Paired structure (grid 8 x 64,
// halves (bx, 15-bx) -> uniform 68 tiles; co-scheduled same-(b,h) blocks = the L2
// strategy). SWAPPED QK^T (T12): s = mfma(K, Q) -> lane l16 holds P[q=l16][keys
// quad*4+j] for both 16-key halves; cvt_pk builds the PV A-fragment in registers
// under vtg's key-interleave permutation -> no P-tile LDS round-trip. K/V LDS:
// involution slot-swizzle sigma(s)=s^((s>>3)&7); V fragments hoisted pre-softmax.
__global__ __launch_bounds__(256, 2) void attn_kernel(const short* __restrict__ qkv,
                                                      const short* __restrict__ vtg,
                                                      short* __restrict__ outp) {
    __shared__ __align__(16) short Ks[2][4096];
    __shared__ __align__(16) short Vt[2][4096];
    const int b = blockIdx.y >> 4, h = blockIdx.y & 15;
    const int tid = threadIdx.x, wave = tid >> 6, lane = tid & 63;
    const int quad = lane >> 4, l16 = lane & 15;
    const size_t baseRow = (size_t)b * N_SEQ;

    // staging: lane l fetches logical slot sigma(l) = l ^ ((l>>3)&7)
    const int sl = lane ^ ((lane >> 3) & 7);
    const int srow = sl >> 2, sq = sl & 3;
    // read: logical slot (l16*4+quad) lives at physical slot ^ ((l16>>1)&7)
    const int rslot = ((l16 * 4 + quad) ^ ((l16 >> 1) & 7)) * 8;

    auto stage = [&](int k0, int bufi) {
#pragma unroll
        for (int i = 0; i < 2; ++i) {
            const int c = wave * 2 + i;
            gld_lds16(qkv + (baseRow + k0 + (c & 1) * 16 + srow) * QKV_LD + E_DIM +
                          (c >> 1) * 32 + sq * 8,
                      &Ks[bufi][c * 512]);
            gld_lds16(vtg + (size_t)(c * 16 + srow) * MROWS_T + baseRow + k0 + sq * 8,
                      &Vt[bufi][c * 512]);
        }
    };

#pragma unroll 1
    for (int half = 0; half < 2; ++half) {
        const int chunk = half ? (15 - blockIdx.x) : blockIdx.x;
        const int q0 = chunk * 128;
        const int wrow = q0 + wave * 32;

        bfx8 aq0[4], aq1[4];
        {
            const short* qb0 = qkv + (baseRow + wrow + l16) * QKV_LD + h * D_HEAD + quad * 8;
            const short* qb1 = qb0 + 16 * QKV_LD;
#pragma unroll
            for (int c = 0; c < 4; ++c) {
                aq0[c] = *(const bfx8*)(qb0 + c * 32);
                aq1[c] = *(const bfx8*)(qb1 + c * 32);
            }
        }

        fx4 accO0[8], accO1[8];
        float l0 = 0.f, l1 = 0.f;
#pragma unroll
        for (int dt = 0; dt < 8; ++dt) {
            accO0[dt] = (fx4){0.f, 0.f, 0.f, 0.f};
            accO1[dt] = (fx4){0.f, 0.f, 0.f, 0.f};
        }

        const int nbulk = 4 * chunk;
        const int nkt = nbulk + 4;

        __syncthreads();   // all waves done reading LDS from previous half
        stage(0, 0);

#pragma unroll 1
        for (int kt = 0; kt < nkt; ++kt) {
            __syncthreads();   // buf[kt&1] ready (vmcnt drain hidden by previous compute)
            if (kt + 1 < nkt) stage((kt + 1) << 5, (kt + 1) & 1);
            const short* ks = Ks[kt & 1];
            const short* vs = Vt[kt & 1];
            const int k0 = kt << 5;

            // SWAPPED S^T = K Q^T: lane l16 holds P[q=l16][key = k0 + 16h + quad*4+j]
            fx4 s00 = {0.f, 0.f, 0.f, 0.f}, s01 = {0.f, 0.f, 0.f, 0.f};
            fx4 s10 = {0.f, 0.f, 0.f, 0.f}, s11 = {0.f, 0.f, 0.f, 0.f};
            __builtin_amdgcn_s_setprio(1);
#pragma unroll
            for (int dc = 0; dc < 4; ++dc) {
                bfx8 kf0 = *(const bfx8*)&ks[(dc * 2 + 0) * 512 + rslot];
                bfx8 kf1 = *(const bfx8*)&ks[(dc * 2 + 1) * 512 + rslot];
                s00 = mfma_bf16(kf0, aq0[dc], s00);
                s01 = mfma_bf16(kf1, aq0[dc], s01);
                s10 = mfma_bf16(kf0, aq1[dc], s10);
                s11 = mfma_bf16(kf1, aq1[dc], s11);
            }
            __builtin_amdgcn_s_setprio(0);

            // hoist V fragments: DS latency overlaps the softmax VALU below
            bfx8 bvr[8];
#pragma unroll
            for (int dt = 0; dt < 8; ++dt)
                bvr[dt] = *(const bfx8*)&vs[dt * 512 + rslot];

            const bool diag = kt >= nbulk;
            int pk0[4], pk1[4];
#pragma unroll
            for (int j = 0; j < 4; ++j) {
                float e0 = __builtin_amdgcn_exp2f(s00[j]);
                float e1 = __builtin_amdgcn_exp2f(s01[j]);
                if (diag) {
                    const int key = k0 + quad * 4 + j;
                    const int qr = wrow + l16;
                    e0 = (key <= qr) ? e0 : 0.f;
                    e1 = (key + 16 <= qr) ? e1 : 0.f;
                }
                l0 += e0 + e1;
                pk0[j] = cvt_pk_bf16(e0, e1);
            }
#pragma unroll
            for (int j = 0; j < 4; ++j) {
                float e0 = __builtin_amdgcn_exp2f(s10[j]);
                float e1 = __builtin_amdgcn_exp2f(s11[j]);
                if (diag) {
                    const int key = k0 + quad * 4 + j;
                    const int qr = wrow + 16 + l16;
                    e0 = (key <= qr) ? e0 : 0.f;
                    e1 = (key + 16 <= qr) ? e1 : 0.f;
                }
                l1 += e0 + e1;
                pk1[j] = cvt_pk_bf16(e0, e1);
            }

            bfx8 ap0 = __builtin_bit_cast(bfx8, (ix4){pk0[0], pk0[1], pk0[2], pk0[3]});
            bfx8 ap1 = __builtin_bit_cast(bfx8, (ix4){pk1[0], pk1[1], pk1[2], pk1[3]});
            __builtin_amdgcn_s_setprio(1);
#pragma unroll
            for (int dt = 0; dt < 8; ++dt) {
                accO0[dt] = mfma_bf16(ap0, bvr[dt], accO0[dt]);
                accO1[dt] = mfma_bf16(ap1, bvr[dt], accO1[dt]);
            }
            __builtin_amdgcn_s_setprio(0);
        }

        // l currently per-lane partial over this quad's keys; reduce across quads
        // (lane bits 4,5) -> every lane holds L[q = wrow (+16) + l16]
        l0 += __shfl_xor(l0, 16); l0 += __shfl_xor(l0, 32);
        l1 += __shfl_xor(l1, 16); l1 += __shfl_xor(l1, 32);

#pragma unroll
        for (int j = 0; j < 4; ++j) {
            // output row q = wrow + quad*4 + j; its L lives at lane l16 = quad*4+j
            float rl0 = 1.0f / __shfl(l0, quad * 4 + j);
            float rl1 = 1.0f / __shfl(l1, quad * 4 + j);
            size_t ob0 = (baseRow + wrow + quad * 4 + j) * (size_t)E_DIM + h * D_HEAD + l16;
            size_t ob1 = ob0 + (size_t)16 * E_DIM;
#pragma unroll
            for (int dt = 0; dt < 8; ++dt) {
                outp[ob0 + dt * 16] = f2bf(accO0[dt][j] * rl0);
                outp[ob1 + dt * 16] = f2bf(accO1[dt][j] * rl1);
            }
        }
    }
}

extern "C" void kernel_launch(void* const* d_in, const int* in_sizes, int n_in,
                              void* d_out, int out_size, void* d_ws, size_t ws_size,
                              hipStream_t stream) {
    const float* x     = (const float*)d_in[0];
    const float* w_qkv = (const float*)d_in[1];
    const float* b_qkv = (const float*)d_in[2];
    const float* w_fc  = (const float*)d_in[3];
    const float* b_fc  = (const float*)d_in[4];
    float* out = (float*)d_out;

    const size_t MROWS = (size_t)B_SZ * N_SEQ;  // 8192
    short* xb    = (short*)d_ws;                         // 8192*2048
    short* wqkvt = xb + MROWS * E_DIM;                   // 2304*2048
    short* wfct  = wqkvt + (size_t)QKV_LD * E_DIM;       // 2048*2048
    short* qkvb  = wfct + (size_t)E_DIM * E_DIM;         // 8192*2304
    short* attnb = qkvb + MROWS * QKV_LD;                // 8192*2048
    short* vtg   = xb;   // reuse: xb dead after QKV GEMM

    cast_f32_bf16<<<dim3((int)(MROWS * E_DIM / 2048)), dim3(256), 0, stream>>>(
        x, xb, (int)(MROWS * E_DIM));
    transpose_cast2<<<dim3(QKV_LD / 32, E_DIM / 32, 2), dim3(32, 8), 0, stream>>>(
        w_qkv, wqkvt, w_fc, wfct);

    // QKV projection, Q columns (0..2047), scaled by SC2F: 256-grid, one clean round
    gemm256<true, true><<<dim3(E_DIM / 256, (int)(MROWS / 256)), dim3(512), 0, stream>>>(
        xb, wqkvt, b_qkv, qkvb, (int)MROWS, E_DIM, QKV_LD, E_DIM);
    // K/V columns (2048..2303), unscaled: small 128-block 128^2 dispatch
    gemm_bt<true, false><<<dim3(2, (int)(MROWS / 128)), dim3(256), 0, stream>>>(
        xb, wqkvt + (size_t)E_DIM * E_DIM, b_qkv + E_DIM, qkvb + E_DIM,
        (int)MROWS, 2 * D_HEAD, QKV_LD, E_DIM);

    v_transpose<<<dim3(MROWS_T / 32, D_HEAD / 32), dim3(32, 8), 0, stream>>>(qkvb, vtg);

    attn_kernel<<<dim3(8, B_SZ * H_NUM), dim3(256), 0, stream>>>(qkvb, vtg, attnb);

    gemm256<false, false><<<dim3(E_DIM / 256, (int)(MROWS / 256)), dim3(512), 0, stream>>>(
        attnb, wfct, b_fc, out, (int)MROWS, E_DIM, E_DIM, E_DIM);
}